// Round 9
// baseline (1181.645 us; speedup 1.0000x reference)
//
#include <hip/hip_runtime.h>
#include <hip/hip_bf16.h>

#define DELTA 2.5749f
#define BN_EPS 1e-5f

typedef __attribute__((ext_vector_type(8))) _Float16 f16x8;
typedef __attribute__((ext_vector_type(4))) _Float16 f16x4;
typedef __attribute__((ext_vector_type(4))) float f32x4;

__device__ inline unsigned short f2h(float f) {
    union { _Float16 h; unsigned short u; } v;
    v.h = (_Float16)f;  // RNE
    return v.u;
}

// ---------------------------------------------------------------- CSR build (XCD-partitioned)
__global__ __launch_bounds__(256) void k_degree(const int* __restrict__ dst,
                                                int* __restrict__ deg, int E, int npp) {
    int part = blockIdx.x & 7;
    int lo = part * npp, hi = lo + npp;
    int stride = (gridDim.x >> 3) * 256;
    for (int e = (blockIdx.x >> 3) * 256 + threadIdx.x; e < E; e += stride) {
        int d = dst[e];
        if (d >= lo && d < hi) atomicAdd(&deg[d], 1);
    }
}

#define SCAN_B 1024
__global__ void k_scan_block(const int* __restrict__ deg, int* __restrict__ excl,
                             int* __restrict__ bsums, int total) {
    __shared__ int s[SCAN_B];
    int t = threadIdx.x, i = blockIdx.x * SCAN_B + t;
    int v = (i < total) ? deg[i] : 0;
    s[t] = v; __syncthreads();
    for (int off = 1; off < SCAN_B; off <<= 1) {
        int x = (t >= off) ? s[t - off] : 0;
        __syncthreads();
        s[t] += x;
        __syncthreads();
    }
    if (i < total) excl[i] = s[t] - v;
    if (t == SCAN_B - 1) bsums[blockIdx.x] = s[t];
}

__global__ void k_scan_tops(int* __restrict__ bsums, int nb) {
    __shared__ int s[SCAN_B];
    int t = threadIdx.x;
    int v = (t < nb) ? bsums[t] : 0;
    s[t] = v; __syncthreads();
    for (int off = 1; off < SCAN_B; off <<= 1) {
        int x = (t >= off) ? s[t - off] : 0;
        __syncthreads();
        s[t] += x;
        __syncthreads();
    }
    if (t < nb) bsums[t] = s[t] - v;  // exclusive
}

__global__ void k_scan_add(int* __restrict__ excl, const int* __restrict__ bsums, int total) {
    int i = blockIdx.x * SCAN_B + threadIdx.x;
    if (i < total) excl[i] += bsums[blockIdx.x];
}

__global__ __launch_bounds__(256) void k_fill(const int* __restrict__ src,
                                              const int* __restrict__ dst,
                                              const int* __restrict__ rowptr,
                                              int* __restrict__ fill,
                                              int* __restrict__ col, int E, int npp) {
    int part = blockIdx.x & 7;
    int lo = part * npp, hi = lo + npp;
    int stride = (gridDim.x >> 3) * 256;
    for (int e = (blockIdx.x >> 3) * 256 + threadIdx.x; e < E; e += stride) {
        int d = dst[e];
        if (d >= lo && d < hi) {
            int pos = rowptr[d] + atomicAdd(&fill[d], 1);
            col[pos] = src[e];
        }
    }
}

// ---------------------------------------------------------------- weight cast f32 -> f16
__global__ void k_castw(const float* __restrict__ w, unsigned short* __restrict__ o, int n4) {
    int i = blockIdx.x * 256 + threadIdx.x;
    if (i < n4) {
        float4 v = ((const float4*)w)[i];
        ushort4 r;
        r.x = f2h(v.x); r.y = f2h(v.y); r.z = f2h(v.z); r.w = f2h(v.w);
        ((ushort4*)o)[i] = r;
    }
}

// ---------------------------------------------------------------- BN affine helpers
__global__ void k_ident(float* __restrict__ aff) {
    int t = threadIdx.x;  // 128
    aff[t] = (t < 64) ? 1.f : 0.f;
}

__global__ void k_bnfin(const float* __restrict__ stat, const float* __restrict__ gamma,
                        const float* __restrict__ beta, float* __restrict__ aff, float invN) {
    int d = threadIdx.x;  // 64
    float mu = stat[d] * invN;
    float var = stat[64 + d] * invN - mu * mu;
    float sc = rsqrtf(var + BN_EPS) * gamma[d];
    aff[d] = sc;
    aff[64 + d] = beta[d] - mu * sc;
}

// ---------------------------------------------------------------- aggregation (BN fused, f16 gather)
#define AGG_ACC4(V)                                                        \
    do {                                                                   \
        float x0 = fmaf((float)V[0], sc4.x, sh4.x);                        \
        float x1 = fmaf((float)V[1], sc4.y, sh4.y);                        \
        float x2 = fmaf((float)V[2], sc4.z, sh4.z);                        \
        float x3 = fmaf((float)V[3], sc4.w, sh4.w);                        \
        sum.x += x0; sum.y += x1; sum.z += x2; sum.w += x3;                \
        sq.x = fmaf(x0, x0, sq.x); sq.y = fmaf(x1, x1, sq.y);              \
        sq.z = fmaf(x2, x2, sq.z); sq.w = fmaf(x3, x3, sq.w);              \
        mx.x = fmaxf(mx.x, x0); mx.y = fmaxf(mx.y, x1);                    \
        mx.z = fmaxf(mx.z, x2); mx.w = fmaxf(mx.w, x3);                    \
    } while (0)

__global__ __launch_bounds__(256) void k_agg(const unsigned short* __restrict__ h16,
                                             const int* __restrict__ rowptr,
                                             const int* __restrict__ col,
                                             const float* __restrict__ aff,
                                             unsigned short* __restrict__ baseF,
                                             float* __restrict__ cnt, int N) {
    int node = blockIdx.x * 4 + (threadIdx.x >> 6);
    int lane = threadIdx.x & 63;
    if (node >= N) return;
    int slot = lane >> 4;        // which of 4 concurrent edges
    int fo = (lane & 15) * 4;    // feature offset
    float4 sc4 = *(const float4*)(aff + fo);
    float4 sh4 = *(const float4*)(aff + 64 + fo);
    const _Float16* hp = (const _Float16*)h16;
    int s0 = rowptr[node], s1 = rowptr[node + 1];
    int deg = s1 - s0;
    float4 sum = make_float4(0.f, 0.f, 0.f, 0.f);
    float4 sq = sum;
    float4 mx = make_float4(-INFINITY, -INFINITY, -INFINITY, -INFINITY);
    int e = s0 + slot;
    for (; e + 12 < s1; e += 16) {
        int sA = col[e], sB = col[e + 4], sC = col[e + 8], sD = col[e + 12];
        f16x4 v1 = *(const f16x4*)(hp + (size_t)sA * 64 + fo);
        f16x4 v2 = *(const f16x4*)(hp + (size_t)sB * 64 + fo);
        f16x4 v3 = *(const f16x4*)(hp + (size_t)sC * 64 + fo);
        f16x4 v4 = *(const f16x4*)(hp + (size_t)sD * 64 + fo);
        AGG_ACC4(v1); AGG_ACC4(v2); AGG_ACC4(v3); AGG_ACC4(v4);
    }
    for (; e < s1; e += 4) {
        int s = col[e];
        f16x4 v = *(const f16x4*)(hp + (size_t)s * 64 + fo);
        AGG_ACC4(v);
    }
#pragma unroll
    for (int m = 16; m <= 32; m <<= 1) {
        sum.x += __shfl_xor(sum.x, m); sum.y += __shfl_xor(sum.y, m);
        sum.z += __shfl_xor(sum.z, m); sum.w += __shfl_xor(sum.w, m);
        sq.x += __shfl_xor(sq.x, m); sq.y += __shfl_xor(sq.y, m);
        sq.z += __shfl_xor(sq.z, m); sq.w += __shfl_xor(sq.w, m);
        mx.x = fmaxf(mx.x, __shfl_xor(mx.x, m)); mx.y = fmaxf(mx.y, __shfl_xor(mx.y, m));
        mx.z = fmaxf(mx.z, __shfl_xor(mx.z, m)); mx.w = fmaxf(mx.w, __shfl_xor(mx.w, m));
    }
    float c = (float)(deg > 0 ? deg : 1);
    float ic = 1.f / c;
    float4 mean = make_float4(sum.x * ic, sum.y * ic, sum.z * ic, sum.w * ic);
    float4 var = make_float4(fmaxf(fmaf(-mean.x, mean.x, sq.x * ic), 0.f),
                             fmaxf(fmaf(-mean.y, mean.y, sq.y * ic), 0.f),
                             fmaxf(fmaf(-mean.z, mean.z, sq.z * ic), 0.f),
                             fmaxf(fmaf(-mean.w, mean.w, sq.w * ic), 0.f));
    if (deg == 0) mx = make_float4(0.f, 0.f, 0.f, 0.f);
    float4 wv = (slot == 0) ? sum : (slot == 1) ? mx : (slot == 2) ? mean : var;
    ushort4 of;
    of.x = f2h(wv.x); of.y = f2h(wv.y); of.z = f2h(wv.z); of.w = f2h(wv.w);
    *(ushort4*)(baseF + (size_t)node * 256 + slot * 64 + fo) = of;
    if (lane == 0) cnt[node] = c;
}

// ---------------------------------------------------------------- big GEMM via MFMA f16 (dbuf weights)
// Weight LDS double-buffered (2 x 24KB): next chunk's global loads issue before this
// chunk's MFMAs, ds_writes after -> staging latency hides under compute. 1 barrier/chunk.
__global__ __launch_bounds__(256) void k_gemm1(const unsigned short* __restrict__ baseF,
                                               const float* __restrict__ cnt,
                                               const unsigned short* __restrict__ mWF,
                                               const float* __restrict__ mb,
                                               const float* __restrict__ hres,
                                               const float* __restrict__ aff,
                                               float* __restrict__ out, int N) {
    __shared__ _Float16 ldsW[2][24 * 512];  // rec = s*12 + mat*4 + nt
    int t = threadIdx.x;
    int wave = t >> 6, lane = t & 63;
    int r16 = lane & 15, quad = lane >> 4;
    int m0 = blockIdx.x * 128 + wave * 32;   // first m-tile; second is m0+16
    const _Float16* aptr0 = (const _Float16*)baseF + (size_t)(m0 + r16) * 256 + quad * 8;
    const _Float16* aptr1 = (const _Float16*)baseF + (size_t)(m0 + 16 + r16) * 256 + quad * 8;

    f32x4 acc0[12], acc1[12];
#pragma unroll
    for (int i = 0; i < 12; i++) {
        acc0[i] = (f32x4){0.f, 0.f, 0.f, 0.f};
        acc1[i] = (f32x4){0.f, 0.f, 0.f, 0.f};
    }
    // A fragments for chunk 0
    f16x8 a00 = *(const f16x8*)(aptr0 + 0);
    f16x8 a01 = *(const f16x8*)(aptr1 + 0);
    f16x8 a10 = *(const f16x8*)(aptr0 + 32);
    f16x8 a11 = *(const f16x8*)(aptr1 + 32);
    // stage chunk 0 weights into buffer 0
#pragma unroll
    for (int rb = 0; rb < 24; rb += 4) {
        int rec = rb + wave;
        int s = rec / 12, tile = rec % 12;
        int mat = tile >> 2, nt = tile & 3;
        uint4 v = *(const uint4*)(mWF + (size_t)(nt * 16 + r16) * 768 + mat * 256
                                  + s * 32 + quad * 8);
        *(uint4*)((unsigned short*)ldsW[0] + rec * 512 + lane * 8) = v;
    }
    __syncthreads();

#pragma unroll 1
    for (int chunk = 0; chunk < 4; chunk++) {
        const _Float16* buf = ldsW[chunk & 1];
        // issue next chunk's weight loads (into regs) BEFORE compute
        uint4 wtmp[6];
        if (chunk < 3) {
#pragma unroll
            for (int rb = 0; rb < 24; rb += 4) {
                int rec = rb + wave;
                int s = rec / 12, tile = rec % 12;
                int mat = tile >> 2, nt = tile & 3;
                wtmp[rb >> 2] = *(const uint4*)(mWF + (size_t)(nt * 16 + r16) * 768 + mat * 256
                                                + (chunk + 1) * 64 + s * 32 + quad * 8);
            }
        }
        // prefetch next chunk's A
        f16x8 n00, n01, n10, n11;
        if (chunk < 3) {
            int ko = (chunk + 1) * 64;
            n00 = *(const f16x8*)(aptr0 + ko);
            n01 = *(const f16x8*)(aptr1 + ko);
            n10 = *(const f16x8*)(aptr0 + ko + 32);
            n11 = *(const f16x8*)(aptr1 + ko + 32);
        }
#pragma unroll
        for (int s = 0; s < 2; s++) {
            f16x8 af0 = s ? a10 : a00;
            f16x8 af1 = s ? a11 : a01;
#pragma unroll
            for (int tile = 0; tile < 12; tile++) {
                f16x8 wF = *(const f16x8*)(buf + (s * 12 + tile) * 512 + lane * 8);
                acc0[tile] = __builtin_amdgcn_mfma_f32_16x16x32_f16(af0, wF, acc0[tile], 0, 0, 0);
                acc1[tile] = __builtin_amdgcn_mfma_f32_16x16x32_f16(af1, wF, acc1[tile], 0, 0, 0);
            }
        }
        if (chunk < 3) {
            unsigned short* nbuf = (unsigned short*)ldsW[(chunk + 1) & 1];
#pragma unroll
            for (int rb = 0; rb < 24; rb += 4) {
                int rec = rb + wave;
                *(uint4*)(nbuf + rec * 512 + lane * 8) = wtmp[rb >> 2];
            }
            __syncthreads();
        }
        a00 = n00; a01 = n01; a10 = n10; a11 = n11;
    }
    float scf[4], shf[4];
#pragma unroll
    for (int nt = 0; nt < 4; nt++) {
        int f = nt * 16 + r16;
        scf[nt] = aff[f]; shf[nt] = aff[64 + f];
    }
#pragma unroll
    for (int mt = 0; mt < 2; mt++) {
#pragma unroll
        for (int i = 0; i < 4; i++) {
            int node = m0 + mt * 16 + quad * 4 + i;
            if (node < N) {
                float c = cnt[node];
                float amp = c / DELTA, att = DELTA / c;
#pragma unroll
                for (int nt = 0; nt < 4; nt++) {
                    int feat = nt * 16 + r16;
                    f32x4* a = mt ? acc1 : acc0;
                    float res = fmaf(hres[(size_t)node * 64 + feat], scf[nt], shf[nt]);
                    float v = a[nt][i] + amp * a[4 + nt][i] + att * a[8 + nt][i]
                            + mb[feat] + res;
                    out[(size_t)node * 64 + feat] = v;
                }
            }
        }
    }
}

// ---------------------------------------------------------------- 64x64 GEMM (encoder / nn1 / nn2)
#define FMA16(ACC0, ACC1, ACC2, ACC3, A, W)                                \
    do {                                                                   \
        ACC0.x = fmaf(A.x, W.x, ACC0.x); ACC0.y = fmaf(A.x, W.y, ACC0.y);  \
        ACC0.z = fmaf(A.x, W.z, ACC0.z); ACC0.w = fmaf(A.x, W.w, ACC0.w);  \
        ACC1.x = fmaf(A.y, W.x, ACC1.x); ACC1.y = fmaf(A.y, W.y, ACC1.y);  \
        ACC1.z = fmaf(A.y, W.z, ACC1.z); ACC1.w = fmaf(A.y, W.w, ACC1.w);  \
        ACC2.x = fmaf(A.z, W.x, ACC2.x); ACC2.y = fmaf(A.z, W.y, ACC2.y);  \
        ACC2.z = fmaf(A.z, W.z, ACC2.z); ACC2.w = fmaf(A.z, W.w, ACC2.w);  \
        ACC3.x = fmaf(A.w, W.x, ACC3.x); ACC3.y = fmaf(A.w, W.y, ACC3.y);  \
        ACC3.z = fmaf(A.w, W.z, ACC3.z); ACC3.w = fmaf(A.w, W.w, ACC3.w);  \
    } while (0)

template <bool RELU, bool BNSTAT>
__global__ __launch_bounds__(256) void k_gemm64(const float* __restrict__ in,
                                                const float* __restrict__ W,
                                                const float* __restrict__ bias,
                                                float* __restrict__ out,
                                                unsigned short* __restrict__ out16,
                                                float* __restrict__ bnstat, int N) {
    __shared__ float sInT[64][64];  // [k][node]
    __shared__ float sWT[64][64];   // [k][feat]
    int t = threadIdx.x;
    int tx = t & 15, ty = t >> 4;
    int n0 = blockIdx.x * 64;
    int c4 = tx * 4;
#pragma unroll
    for (int ch = 0; ch < 4; ch++) {
        int row = ch * 16 + ty;
        float4 v = make_float4(0.f, 0.f, 0.f, 0.f);
        if (n0 + row < N) v = *(const float4*)(in + (size_t)(n0 + row) * 64 + c4);
        sInT[c4 + 0][row] = v.x; sInT[c4 + 1][row] = v.y;
        sInT[c4 + 2][row] = v.z; sInT[c4 + 3][row] = v.w;
        float4 w = *(const float4*)(W + (size_t)row * 64 + c4);
        sWT[c4 + 0][row] = w.x; sWT[c4 + 1][row] = w.y;
        sWT[c4 + 2][row] = w.z; sWT[c4 + 3][row] = w.w;
    }
    __syncthreads();
    float4 acc0 = make_float4(0.f, 0.f, 0.f, 0.f);
    float4 acc1 = acc0, acc2 = acc0, acc3 = acc0;
#pragma unroll 8
    for (int k = 0; k < 64; k++) {
        float4 a = *(const float4*)(&sInT[k][ty * 4]);
        float4 w = *(const float4*)(&sWT[k][tx * 4]);
        FMA16(acc0, acc1, acc2, acc3, a, w);
    }
    float4 b4 = *(const float4*)(bias + tx * 4);
    float4 s1 = make_float4(0.f, 0.f, 0.f, 0.f);
    float4 s2 = s1;
#pragma unroll
    for (int i = 0; i < 4; i++) {
        int n = n0 + ty * 4 + i;
        if (n < N) {
            float4 v = (i == 0) ? acc0 : (i == 1) ? acc1 : (i == 2) ? acc2 : acc3;
            v.x += b4.x; v.y += b4.y; v.z += b4.z; v.w += b4.w;
            if (RELU) {
                v.x = fmaxf(v.x, 0.f); v.y = fmaxf(v.y, 0.f);
                v.z = fmaxf(v.z, 0.f); v.w = fmaxf(v.w, 0.f);
            }
            *(float4*)(out + (size_t)n * 64 + tx * 4) = v;
            if (out16) {
                ushort4 o;
                o.x = f2h(v.x); o.y = f2h(v.y); o.z = f2h(v.z); o.w = f2h(v.w);
                *(ushort4*)(out16 + (size_t)n * 64 + tx * 4) = o;
            }
            if (BNSTAT) {
                s1.x += v.x; s1.y += v.y; s1.z += v.z; s1.w += v.w;
                s2.x = fmaf(v.x, v.x, s2.x); s2.y = fmaf(v.y, v.y, s2.y);
                s2.z = fmaf(v.z, v.z, s2.z); s2.w = fmaf(v.w, v.w, s2.w);
            }
        }
    }
    if (BNSTAT) {
        __syncthreads();
        float* red = &sInT[0][0];
        *(float4*)(red + ty * 64 + tx * 4) = s1;
        *(float4*)(red + 1024 + ty * 64 + tx * 4) = s2;
        __syncthreads();
        if (t < 128) {
            int d = t & 63;
            int base = (t >> 6) * 1024;
            float tot = 0.f;
#pragma unroll
            for (int r2 = 0; r2 < 16; r2++) tot += red[base + r2 * 64 + d];
            atomicAdd(&bnstat[(t >> 6) * 64 + d], tot);
        }
    }
}

// ---------------------------------------------------------------- pool (batch sorted; BN fused)
__global__ void k_pool(const float* __restrict__ h, const int* __restrict__ batch,
                       const float* __restrict__ aff, float* __restrict__ g, int N) {
    int d = threadIdx.x & 63, r = threadIdx.x >> 6;
    float sc = aff[d], sh = aff[64 + d];
    int nbase = blockIdx.x * 32;
    float acc = 0.f;
    int gcur = -1;
    for (int i = 0; i < 8; i++) {
        int n = nbase + i * 4 + r;
        if (n < N) {
            int gb = batch[n];
            if (gb != gcur) {
                if (gcur >= 0) atomicAdd(&g[gcur * 64 + d], acc);
                acc = 0.f; gcur = gb;
            }
            acc += fmaf(h[(size_t)n * 64 + d], sc, sh);
        }
    }
    if (gcur >= 0) atomicAdd(&g[gcur * 64 + d], acc);
}

// ---------------------------------------------------------------- head: relu(g@fc1)+fc2
__global__ void k_head(const float* __restrict__ g, const float* __restrict__ fc1W,
                       const float* __restrict__ fc1b, const float* __restrict__ fc2W,
                       const float* __restrict__ fc2b, float* __restrict__ out) {
    __shared__ float sg[64], sg1[64];
    int gi = blockIdx.x, t = threadIdx.x;
    sg[t] = g[gi * 64 + t];
    __syncthreads();
    float a = fc1b[t];
    for (int k = 0; k < 64; k++) a = fmaf(sg[k], fc1W[t * 64 + k], a);
    sg1[t] = fmaxf(a, 0.f);
    __syncthreads();
    if (t < 16) {
        float o = fc2b[t];
        for (int k = 0; k < 64; k++) o = fmaf(sg1[k], fc2W[t * 64 + k], o);
        out[gi * 16 + t] = o;
    }
}

// ---------------------------------------------------------------- launcher
extern "C" void kernel_launch(void* const* d_in, const int* in_sizes, int n_in,
                              void* d_out, int out_size, void* d_ws, size_t ws_size,
                              hipStream_t stream) {
    const float* x       = (const float*)d_in[0];
    const int*   eidx    = (const int*)d_in[1];
    const int*   batch   = (const int*)d_in[2];
    const float* encW    = (const float*)d_in[3];
    const float* encb    = (const float*)d_in[4];
    const float* nnW1    = (const float*)d_in[5];
    const float* nnb1    = (const float*)d_in[6];
    const float* nnW2    = (const float*)d_in[7];
    const float* nnb2    = (const float*)d_in[8];
    const float* mlpW    = (const float*)d_in[9];
    const float* mlpb    = (const float*)d_in[10];
    const float* bnG     = (const float*)d_in[11];
    const float* bnB     = (const float*)d_in[12];
    const float* fc1W    = (const float*)d_in[13];
    const float* fc1b    = (const float*)d_in[14];
    const float* fc2W    = (const float*)d_in[15];
    const float* fc2b    = (const float*)d_in[16];
    float* out = (float*)d_out;

    const int N = in_sizes[0] / 64;
    const int E = in_sizes[1] / 2;
    const int G = 512;
    const int* src = eidx;
    const int* dst = eidx + E;
    const int npp = (N + 7) / 8;  // nodes per XCD partition

    // workspace layout
    char* ws = (char*)d_ws;
    size_t off = 0;
    auto alloc = [&](size_t bytes) { size_t r = off; off = (off + bytes + 255) & ~(size_t)255; return r; };
    int*   deg     = (int*)(ws + alloc((size_t)(N + 1) * 4));
    int*   rowptr  = (int*)(ws + alloc((size_t)(N + 1) * 4));
    int*   bsums   = (int*)(ws + alloc(1024 * 4));
    int*   fill    = (int*)(ws + alloc((size_t)N * 4));
    int*   col     = (int*)(ws + alloc((size_t)E * 4));
    float* cnt     = (float*)(ws + alloc((size_t)N * 4));
    unsigned short* baseF = (unsigned short*)(ws + alloc((size_t)N * 256 * 2 + 131072));  // +pad for OOB tile reads
    float* hA      = (float*)(ws + alloc((size_t)N * 64 * 4));
    float* hB      = (float*)(ws + alloc((size_t)N * 64 * 4));
    float* hC      = (float*)(ws + alloc((size_t)N * 64 * 4));
    unsigned short* hC16 = (unsigned short*)(ws + alloc((size_t)N * 64 * 2));
    unsigned short* mWF = (unsigned short*)(ws + alloc((size_t)5 * 64 * 768 * 2));
    float* bnstats = (float*)(ws + alloc(5 * 128 * 4));
    float* affbuf  = (float*)(ws + alloc(6 * 128 * 4));
    float* gpool   = (float*)(ws + alloc((size_t)G * 64 * 4));

    hipMemsetAsync(deg, 0, (size_t)(N + 1) * 4, stream);
    hipMemsetAsync(fill, 0, (size_t)N * 4, stream);
    hipMemsetAsync(bnstats, 0, 5 * 128 * 4, stream);
    hipMemsetAsync(gpool, 0, (size_t)G * 64 * 4, stream);

    int total = N + 1;
    int nscan = (total + SCAN_B - 1) / SCAN_B;
    int ngrid64 = (N + 63) / 64;
    int ngrid128 = (N + 127) / 128;

    k_degree<<<1024, 256, 0, stream>>>(dst, deg, E, npp);
    k_scan_block<<<nscan, SCAN_B, 0, stream>>>(deg, rowptr, bsums, total);
    k_scan_tops<<<1, SCAN_B, 0, stream>>>(bsums, nscan);
    k_scan_add<<<nscan, SCAN_B, 0, stream>>>(rowptr, bsums, total);
    k_fill<<<1024, 256, 0, stream>>>(src, dst, rowptr, fill, col, E, npp);

    // cast all 5 layers' mlpW to f16 (5*64*768 = 245760 floats = 61440 float4)
    k_castw<<<240, 256, 0, stream>>>(mlpW, mWF, 61440);
    k_ident<<<1, 128, 0, stream>>>(affbuf);

    // encoder: hC = x @ encW.T + encb (also emits f16 copy for the gather)
    k_gemm64<false, false><<<ngrid64, 256, 0, stream>>>(x, encW, encb, hC, hC16, nullptr, N);

    for (int i = 0; i < 5; i++) {
        const float* aff = affbuf + i * 128;
        k_agg<<<(N + 3) / 4, 256, 0, stream>>>(hC16, rowptr, col, aff, baseF, cnt, N);
        k_gemm1<<<ngrid128, 256, 0, stream>>>(baseF, cnt,
                                              mWF + (size_t)i * 64 * 768,
                                              mlpb + i * 64, hC, aff, hA, N);
        k_gemm64<true, false><<<ngrid64, 256, 0, stream>>>(hA, nnW1 + (size_t)i * 4096,
                                                           nnb1 + i * 64, hB, nullptr, nullptr, N);
        k_gemm64<true, true><<<ngrid64, 256, 0, stream>>>(hB, nnW2 + (size_t)i * 4096,
                                                          nnb2 + i * 64, hC, hC16,
                                                          bnstats + i * 128, N);
        k_bnfin<<<1, 64, 0, stream>>>(bnstats + i * 128, bnG + i * 64, bnB + i * 64,
                                      affbuf + (i + 1) * 128, 1.f / (float)N);
    }

    k_pool<<<(N + 31) / 32, 256, 0, stream>>>(hC, batch, affbuf + 5 * 128, gpool, N);
    k_head<<<G, 64, 0, stream>>>(gpool, fc1W, fc1b, fc2W, fc2b, out);
}

// Round 10
// 943.853 us; speedup vs baseline: 1.2519x; 1.2519x over previous
//
#include <hip/hip_runtime.h>
#include <hip/hip_bf16.h>

#define DELTA 2.5749f
#define BN_EPS 1e-5f

typedef __attribute__((ext_vector_type(8))) _Float16 f16x8;
typedef __attribute__((ext_vector_type(4))) float f32x4;

__device__ inline unsigned short f2h(float f) {
    union { _Float16 h; unsigned short u; } v;
    v.h = (_Float16)f;  // RNE
    return v.u;
}

// ---------------------------------------------------------------- CSR build (XCD-partitioned)
__global__ __launch_bounds__(256) void k_degree(const int* __restrict__ dst,
                                                int* __restrict__ deg, int E, int npp) {
    int part = blockIdx.x & 7;
    int lo = part * npp, hi = lo + npp;
    int stride = (gridDim.x >> 3) * 256;
    for (int e = (blockIdx.x >> 3) * 256 + threadIdx.x; e < E; e += stride) {
        int d = dst[e];
        if (d >= lo && d < hi) atomicAdd(&deg[d], 1);
    }
}

#define SCAN_B 1024
__global__ void k_scan_block(const int* __restrict__ deg, int* __restrict__ excl,
                             int* __restrict__ bsums, int total) {
    __shared__ int s[SCAN_B];
    int t = threadIdx.x, i = blockIdx.x * SCAN_B + t;
    int v = (i < total) ? deg[i] : 0;
    s[t] = v; __syncthreads();
    for (int off = 1; off < SCAN_B; off <<= 1) {
        int x = (t >= off) ? s[t - off] : 0;
        __syncthreads();
        s[t] += x;
        __syncthreads();
    }
    if (i < total) excl[i] = s[t] - v;
    if (t == SCAN_B - 1) bsums[blockIdx.x] = s[t];
}

__global__ void k_scan_tops(int* __restrict__ bsums, int nb) {
    __shared__ int s[SCAN_B];
    int t = threadIdx.x;
    int v = (t < nb) ? bsums[t] : 0;
    s[t] = v; __syncthreads();
    for (int off = 1; off < SCAN_B; off <<= 1) {
        int x = (t >= off) ? s[t - off] : 0;
        __syncthreads();
        s[t] += x;
        __syncthreads();
    }
    if (t < nb) bsums[t] = s[t] - v;  // exclusive
}

__global__ void k_scan_add(int* __restrict__ excl, const int* __restrict__ bsums, int total) {
    int i = blockIdx.x * SCAN_B + threadIdx.x;
    if (i < total) excl[i] += bsums[blockIdx.x];
}

__global__ __launch_bounds__(256) void k_fill(const int* __restrict__ src,
                                              const int* __restrict__ dst,
                                              const int* __restrict__ rowptr,
                                              int* __restrict__ fill,
                                              int* __restrict__ col, int E, int npp) {
    int part = blockIdx.x & 7;
    int lo = part * npp, hi = lo + npp;
    int stride = (gridDim.x >> 3) * 256;
    for (int e = (blockIdx.x >> 3) * 256 + threadIdx.x; e < E; e += stride) {
        int d = dst[e];
        if (d >= lo && d < hi) {
            int pos = rowptr[d] + atomicAdd(&fill[d], 1);
            col[pos] = src[e];
        }
    }
}

// ---------------------------------------------------------------- weight cast f32 -> f16
__global__ void k_castw(const float* __restrict__ w, unsigned short* __restrict__ o, int n4) {
    int i = blockIdx.x * 256 + threadIdx.x;
    if (i < n4) {
        float4 v = ((const float4*)w)[i];
        ushort4 r;
        r.x = f2h(v.x); r.y = f2h(v.y); r.z = f2h(v.z); r.w = f2h(v.w);
        ((ushort4*)o)[i] = r;
    }
}

// ---------------------------------------------------------------- BN affine helpers
__global__ void k_ident(float* __restrict__ aff) {
    int t = threadIdx.x;  // 128
    aff[t] = (t < 64) ? 1.f : 0.f;
}

__global__ void k_bnfin(const float* __restrict__ stat, const float* __restrict__ gamma,
                        const float* __restrict__ beta, float* __restrict__ aff, float invN) {
    int d = threadIdx.x;  // 64
    float mu = stat[d] * invN;
    float var = stat[64 + d] * invN - mu * mu;
    float sc = rsqrtf(var + BN_EPS) * gamma[d];
    aff[d] = sc;
    aff[64 + d] = beta[d] - mu * sc;
}

// ---------------------------------------------------------------- aggregation
// 8 lanes per edge (f16x8 = 16B/lane), 8 edges in flight per instruction, unroll 2.
#define AGG_ACC8(V)                                                        \
    do {                                                                   \
        float x0 = fmaf((float)V[0], scL.x, shL.x);                        \
        float x1 = fmaf((float)V[1], scL.y, shL.y);                        \
        float x2 = fmaf((float)V[2], scL.z, shL.z);                        \
        float x3 = fmaf((float)V[3], scL.w, shL.w);                        \
        float x4 = fmaf((float)V[4], scH.x, shH.x);                        \
        float x5 = fmaf((float)V[5], scH.y, shH.y);                        \
        float x6 = fmaf((float)V[6], scH.z, shH.z);                        \
        float x7 = fmaf((float)V[7], scH.w, shH.w);                        \
        sumL.x += x0; sumL.y += x1; sumL.z += x2; sumL.w += x3;            \
        sumH.x += x4; sumH.y += x5; sumH.z += x6; sumH.w += x7;            \
        sqL.x = fmaf(x0, x0, sqL.x); sqL.y = fmaf(x1, x1, sqL.y);          \
        sqL.z = fmaf(x2, x2, sqL.z); sqL.w = fmaf(x3, x3, sqL.w);          \
        sqH.x = fmaf(x4, x4, sqH.x); sqH.y = fmaf(x5, x5, sqH.y);          \
        sqH.z = fmaf(x6, x6, sqH.z); sqH.w = fmaf(x7, x7, sqH.w);          \
        mxL.x = fmaxf(mxL.x, x0); mxL.y = fmaxf(mxL.y, x1);                \
        mxL.z = fmaxf(mxL.z, x2); mxL.w = fmaxf(mxL.w, x3);                \
        mxH.x = fmaxf(mxH.x, x4); mxH.y = fmaxf(mxH.y, x5);                \
        mxH.z = fmaxf(mxH.z, x6); mxH.w = fmaxf(mxH.w, x7);                \
    } while (0)

#define RED8(OP, A)                                                        \
    do {                                                                   \
        A.x = OP(A.x, __shfl_xor(A.x, m)); A.y = OP(A.y, __shfl_xor(A.y, m)); \
        A.z = OP(A.z, __shfl_xor(A.z, m)); A.w = OP(A.w, __shfl_xor(A.w, m)); \
    } while (0)

__device__ inline float addf(float a, float b) { return a + b; }

__global__ __launch_bounds__(256) void k_agg(const unsigned short* __restrict__ h16,
                                             const int* __restrict__ rowptr,
                                             const int* __restrict__ col,
                                             const float* __restrict__ aff,
                                             unsigned short* __restrict__ baseF,
                                             float* __restrict__ cnt, int N) {
    int node = blockIdx.x * 4 + (threadIdx.x >> 6);
    int lane = threadIdx.x & 63;
    if (node >= N) return;
    int slot = lane >> 3;        // 8 concurrent edges
    int fo = (lane & 7) * 8;     // 8 features per lane
    float4 scL = *(const float4*)(aff + fo);
    float4 scH = *(const float4*)(aff + fo + 4);
    float4 shL = *(const float4*)(aff + 64 + fo);
    float4 shH = *(const float4*)(aff + 64 + fo + 4);
    const _Float16* hp = (const _Float16*)h16;
    int s0 = rowptr[node], s1 = rowptr[node + 1];
    int deg = s1 - s0;
    float4 sumL = make_float4(0.f, 0.f, 0.f, 0.f), sumH = sumL;
    float4 sqL = sumL, sqH = sumL;
    float4 mxL = make_float4(-INFINITY, -INFINITY, -INFINITY, -INFINITY), mxH = mxL;
    int e = s0 + slot;
    for (; e + 8 < s1; e += 16) {
        int sA = col[e], sB = col[e + 8];
        f16x8 v1 = *(const f16x8*)(hp + (size_t)sA * 64 + fo);
        f16x8 v2 = *(const f16x8*)(hp + (size_t)sB * 64 + fo);
        AGG_ACC8(v1); AGG_ACC8(v2);
    }
    if (e < s1) {
        int s = col[e];
        f16x8 v = *(const f16x8*)(hp + (size_t)s * 64 + fo);
        AGG_ACC8(v);
    }
    // butterfly reduce across the 8 slots (lane xor 8, 16, 32)
#pragma unroll
    for (int m = 8; m <= 32; m <<= 1) {
        RED8(addf, sumL); RED8(addf, sumH);
        RED8(addf, sqL); RED8(addf, sqH);
        RED8(fmaxf, mxL); RED8(fmaxf, mxH);
    }
    float c = (float)(deg > 0 ? deg : 1);
    float ic = 1.f / c;
    if (deg == 0) { mxL = make_float4(0.f, 0.f, 0.f, 0.f); mxH = mxL; }
    if (slot < 4) {
        float w[8];
        if (slot == 0) {
            w[0]=sumL.x; w[1]=sumL.y; w[2]=sumL.z; w[3]=sumL.w;
            w[4]=sumH.x; w[5]=sumH.y; w[6]=sumH.z; w[7]=sumH.w;
        } else if (slot == 1) {
            w[0]=mxL.x; w[1]=mxL.y; w[2]=mxL.z; w[3]=mxL.w;
            w[4]=mxH.x; w[5]=mxH.y; w[6]=mxH.z; w[7]=mxH.w;
        } else if (slot == 2) {
            w[0]=sumL.x*ic; w[1]=sumL.y*ic; w[2]=sumL.z*ic; w[3]=sumL.w*ic;
            w[4]=sumH.x*ic; w[5]=sumH.y*ic; w[6]=sumH.z*ic; w[7]=sumH.w*ic;
        } else {
            float m0=sumL.x*ic, m1=sumL.y*ic, m2=sumL.z*ic, m3=sumL.w*ic;
            float m4=sumH.x*ic, m5=sumH.y*ic, m6=sumH.z*ic, m7=sumH.w*ic;
            w[0]=fmaxf(fmaf(-m0,m0,sqL.x*ic),0.f); w[1]=fmaxf(fmaf(-m1,m1,sqL.y*ic),0.f);
            w[2]=fmaxf(fmaf(-m2,m2,sqL.z*ic),0.f); w[3]=fmaxf(fmaf(-m3,m3,sqL.w*ic),0.f);
            w[4]=fmaxf(fmaf(-m4,m4,sqH.x*ic),0.f); w[5]=fmaxf(fmaf(-m5,m5,sqH.y*ic),0.f);
            w[6]=fmaxf(fmaf(-m6,m6,sqH.z*ic),0.f); w[7]=fmaxf(fmaf(-m7,m7,sqH.w*ic),0.f);
        }
        f16x8 hv;
#pragma unroll
        for (int j = 0; j < 8; j++) hv[j] = (_Float16)w[j];
        *(f16x8*)(baseF + (size_t)node * 256 + slot * 64 + fo) = hv;
    }
    if (lane == 0) cnt[node] = c;
}

// ---------------------------------------------------------------- fused per-layer MLP
// Phase0: PNA triple GEMM (f16 MFMA, K=256, weights LDS-staged per 64-k chunk)
// Phase1: +bias +scalers +BN-affine residual -> bufA (f16, LDS)
// Phase2: nn1 GEMM (f16 MFMA from bufA) + relu -> bufB
// Phase3: nn2 GEMM + relu -> bufA + bnstat partials
// Phase4: coalesced hOut16 store + bnstat reduce. Block = 256 thr / 128 nodes.
__global__ __launch_bounds__(256) void k_mlp(const unsigned short* __restrict__ baseF,
                                             const float* __restrict__ cnt,
                                             const unsigned short* __restrict__ mWF,
                                             const float* __restrict__ mb,
                                             const unsigned short* __restrict__ hres16,
                                             const float* __restrict__ aff,
                                             const unsigned short* __restrict__ w1F,
                                             const float* __restrict__ b1,
                                             const unsigned short* __restrict__ w2F,
                                             const float* __restrict__ b2,
                                             float* __restrict__ bnstat,
                                             unsigned short* __restrict__ hOut16, int N) {
    __shared__ char smem[61440];
    _Float16* ldsW = (_Float16*)smem;             // 24 KB (reused as `red` later)
    _Float16* bufA = (_Float16*)(smem + 24576);   // [128][72] f16
    _Float16* bufB = bufA + 128 * 72;             // [128][72] f16
    float* red = (float*)smem;                    // 8 KB reuse of ldsW region

    int t = threadIdx.x;
    int wave = t >> 6, lane = t & 63;
    int r16 = lane & 15, quad = lane >> 4;
    int n0 = blockIdx.x * 128;
    int m0 = n0 + wave * 32;

    // ---------------- Phase 0: base[N,256] x 3 matrices
    const _Float16* aptr0 = (const _Float16*)baseF + (size_t)(m0 + r16) * 256 + quad * 8;
    const _Float16* aptr1 = aptr0 + 16 * 256;
    f32x4 acc0[12], acc1[12];
#pragma unroll
    for (int i = 0; i < 12; i++) {
        acc0[i] = (f32x4){0.f, 0.f, 0.f, 0.f};
        acc1[i] = (f32x4){0.f, 0.f, 0.f, 0.f};
    }
    f16x8 a00 = *(const f16x8*)(aptr0 + 0);
    f16x8 a01 = *(const f16x8*)(aptr1 + 0);
    f16x8 a10 = *(const f16x8*)(aptr0 + 32);
    f16x8 a11 = *(const f16x8*)(aptr1 + 32);

#pragma unroll 1
    for (int chunk = 0; chunk < 4; chunk++) {
        if (chunk) __syncthreads();
#pragma unroll
        for (int rb = 0; rb < 24; rb += 4) {
            int rec = rb + wave;
            int s = rec / 12, tile = rec % 12;
            int mat = tile >> 2, nt = tile & 3;
            uint4 v = *(const uint4*)(mWF + (size_t)(nt * 16 + r16) * 768 + mat * 256
                                      + chunk * 64 + s * 32 + quad * 8);
            *(uint4*)((unsigned short*)ldsW + rec * 512 + lane * 8) = v;
        }
        __syncthreads();
        f16x8 n00, n01, n10, n11;
        if (chunk < 3) {
            int ko = (chunk + 1) * 64;
            n00 = *(const f16x8*)(aptr0 + ko);
            n01 = *(const f16x8*)(aptr1 + ko);
            n10 = *(const f16x8*)(aptr0 + ko + 32);
            n11 = *(const f16x8*)(aptr1 + ko + 32);
        }
#pragma unroll
        for (int s = 0; s < 2; s++) {
            f16x8 af0 = s ? a10 : a00;
            f16x8 af1 = s ? a11 : a01;
#pragma unroll
            for (int tile = 0; tile < 12; tile++) {
                f16x8 wF = *(const f16x8*)(ldsW + (s * 12 + tile) * 512 + lane * 8);
                acc0[tile] = __builtin_amdgcn_mfma_f32_16x16x32_f16(af0, wF, acc0[tile], 0, 0, 0);
                acc1[tile] = __builtin_amdgcn_mfma_f32_16x16x32_f16(af1, wF, acc1[tile], 0, 0, 0);
            }
        }
        a00 = n00; a01 = n01; a10 = n10; a11 = n11;
    }
    __syncthreads();

    // ---------------- Phase 1a: residual copy into bufA (coalesced)
    {
        int nl = t >> 1, fo = (t & 1) * 32;
        int gn = n0 + nl;
        uint4* dp = (uint4*)(bufA + nl * 72 + fo);
        if (gn < N) {
            const uint4* sp = (const uint4*)(hres16 + (size_t)gn * 64 + fo);
            dp[0] = sp[0]; dp[1] = sp[1]; dp[2] = sp[2]; dp[3] = sp[3];
        } else {
            uint4 z = make_uint4(0, 0, 0, 0);
            dp[0] = z; dp[1] = z; dp[2] = z; dp[3] = z;
        }
    }
    __syncthreads();

    // ---------------- Phase 1b: combine accs + bias + scalers + affine residual
    float scf[4], shf[4], mbv[4];
#pragma unroll
    for (int nt = 0; nt < 4; nt++) {
        int f = nt * 16 + r16;
        scf[nt] = aff[f]; shf[nt] = aff[64 + f]; mbv[nt] = mb[f];
    }
#pragma unroll
    for (int mt = 0; mt < 2; mt++) {
#pragma unroll
        for (int i = 0; i < 4; i++) {
            int nl = wave * 32 + mt * 16 + quad * 4 + i;
            int gn = n0 + nl;
            if (gn < N) {
                float c = cnt[gn];
                float amp = c / DELTA, att = DELTA / c;
                f32x4* a = mt ? acc1 : acc0;
#pragma unroll
                for (int nt = 0; nt < 4; nt++) {
                    int f = nt * 16 + r16;
                    float r = (float)bufA[nl * 72 + f];
                    float v = a[nt][i] + amp * a[4 + nt][i] + att * a[8 + nt][i]
                            + mbv[nt] + fmaf(r, scf[nt], shf[nt]);
                    bufA[nl * 72 + f] = (_Float16)v;
                }
            }
        }
    }
    __syncthreads();

    // ---------------- Phase 2: nn1 (relu(t @ W1 + b1)) -> bufB
    f32x4 accN[8];
#pragma unroll
    for (int i = 0; i < 8; i++) accN[i] = (f32x4){0.f, 0.f, 0.f, 0.f};
#pragma unroll
    for (int s = 0; s < 2; s++) {
        f16x8 fA0 = *(const f16x8*)(bufA + (wave * 32 + r16) * 72 + s * 32 + quad * 8);
        f16x8 fA1 = *(const f16x8*)(bufA + (wave * 32 + 16 + r16) * 72 + s * 32 + quad * 8);
#pragma unroll
        for (int nt = 0; nt < 4; nt++) {
            f16x8 wB = *(const f16x8*)((const _Float16*)w1F + (size_t)(nt * 16 + r16) * 64
                                       + s * 32 + quad * 8);
            accN[nt]     = __builtin_amdgcn_mfma_f32_16x16x32_f16(fA0, wB, accN[nt], 0, 0, 0);
            accN[4 + nt] = __builtin_amdgcn_mfma_f32_16x16x32_f16(fA1, wB, accN[4 + nt], 0, 0, 0);
        }
    }
    float b1v[4];
#pragma unroll
    for (int nt = 0; nt < 4; nt++) b1v[nt] = b1[nt * 16 + r16];
#pragma unroll
    for (int mt = 0; mt < 2; mt++) {
#pragma unroll
        for (int i = 0; i < 4; i++) {
            int nl = wave * 32 + mt * 16 + quad * 4 + i;
#pragma unroll
            for (int nt = 0; nt < 4; nt++) {
                float v = fmaxf(accN[mt * 4 + nt][i] + b1v[nt], 0.f);
                bufB[nl * 72 + nt * 16 + r16] = (_Float16)v;
            }
        }
    }
    __syncthreads();

    // ---------------- Phase 3: nn2 (relu(u @ W2 + b2)) -> bufA + bnstat partials
    f32x4 accM[8];
#pragma unroll
    for (int i = 0; i < 8; i++) accM[i] = (f32x4){0.f, 0.f, 0.f, 0.f};
#pragma unroll
    for (int s = 0; s < 2; s++) {
        f16x8 fA0 = *(const f16x8*)(bufB + (wave * 32 + r16) * 72 + s * 32 + quad * 8);
        f16x8 fA1 = *(const f16x8*)(bufB + (wave * 32 + 16 + r16) * 72 + s * 32 + quad * 8);
#pragma unroll
        for (int nt = 0; nt < 4; nt++) {
            f16x8 wB = *(const f16x8*)((const _Float16*)w2F + (size_t)(nt * 16 + r16) * 64
                                       + s * 32 + quad * 8);
            accM[nt]     = __builtin_amdgcn_mfma_f32_16x16x32_f16(fA0, wB, accM[nt], 0, 0, 0);
            accM[4 + nt] = __builtin_amdgcn_mfma_f32_16x16x32_f16(fA1, wB, accM[4 + nt], 0, 0, 0);
        }
    }
    float b2v[4], s1[4], s2[4];
#pragma unroll
    for (int nt = 0; nt < 4; nt++) {
        b2v[nt] = b2[nt * 16 + r16]; s1[nt] = 0.f; s2[nt] = 0.f;
    }
#pragma unroll
    for (int mt = 0; mt < 2; mt++) {
#pragma unroll
        for (int i = 0; i < 4; i++) {
            int nl = wave * 32 + mt * 16 + quad * 4 + i;
            bool ok = (n0 + nl) < N;
#pragma unroll
            for (int nt = 0; nt < 4; nt++) {
                float v = fmaxf(accM[mt * 4 + nt][i] + b2v[nt], 0.f);
                if (ok) { s1[nt] += v; s2[nt] = fmaf(v, v, s2[nt]); }
                bufA[nl * 72 + nt * 16 + r16] = (_Float16)v;
            }
        }
    }
#pragma unroll
    for (int nt = 0; nt < 4; nt++) {
        int row = wave * 4 + quad;
        red[row * 64 + nt * 16 + r16] = s1[nt];
        red[1024 + row * 64 + nt * 16 + r16] = s2[nt];
    }
    __syncthreads();

    // ---------------- Phase 4: coalesced store + bnstat reduce
    {
        int nl = t >> 1, fo = (t & 1) * 32;
        int gn = n0 + nl;
        if (gn < N) {
            const uint4* sp = (const uint4*)(bufA + nl * 72 + fo);
            uint4* dp = (uint4*)(hOut16 + (size_t)gn * 64 + fo);
            dp[0] = sp[0]; dp[1] = sp[1]; dp[2] = sp[2]; dp[3] = sp[3];
        }
    }
    if (t < 128) {
        int d = t & 63, part = t >> 6;
        float tot = 0.f;
#pragma unroll
        for (int r = 0; r < 16; r++) tot += red[part * 1024 + r * 64 + d];
        atomicAdd(&bnstat[part * 64 + d], tot);
    }
}

// ---------------------------------------------------------------- 64x64 GEMM (encoder only)
#define FMA16(ACC0, ACC1, ACC2, ACC3, A, W)                                \
    do {                                                                   \
        ACC0.x = fmaf(A.x, W.x, ACC0.x); ACC0.y = fmaf(A.x, W.y, ACC0.y);  \
        ACC0.z = fmaf(A.x, W.z, ACC0.z); ACC0.w = fmaf(A.x, W.w, ACC0.w);  \
        ACC1.x = fmaf(A.y, W.x, ACC1.x); ACC1.y = fmaf(A.y, W.y, ACC1.y);  \
        ACC1.z = fmaf(A.y, W.z, ACC1.z); ACC1.w = fmaf(A.y, W.w, ACC1.w);  \
        ACC2.x = fmaf(A.z, W.x, ACC2.x); ACC2.y = fmaf(A.z, W.y, ACC2.y);  \
        ACC2.z = fmaf(A.z, W.z, ACC2.z); ACC2.w = fmaf(A.z, W.w, ACC2.w);  \
        ACC3.x = fmaf(A.w, W.x, ACC3.x); ACC3.y = fmaf(A.w, W.y, ACC3.y);  \
        ACC3.z = fmaf(A.w, W.z, ACC3.z); ACC3.w = fmaf(A.w, W.w, ACC3.w);  \
    } while (0)

__global__ __launch_bounds__(256) void k_gemm64(const float* __restrict__ in,
                                                const float* __restrict__ W,
                                                const float* __restrict__ bias,
                                                unsigned short* __restrict__ out16, int N) {
    __shared__ float sInT[64][64];  // [k][node]
    __shared__ float sWT[64][64];   // [k][feat]
    int t = threadIdx.x;
    int tx = t & 15, ty = t >> 4;
    int n0 = blockIdx.x * 64;
    int c4 = tx * 4;
#pragma unroll
    for (int ch = 0; ch < 4; ch++) {
        int row = ch * 16 + ty;
        float4 v = make_float4(0.f, 0.f, 0.f, 0.f);
        if (n0 + row < N) v = *(const float4*)(in + (size_t)(n0 + row) * 64 + c4);
        sInT[c4 + 0][row] = v.x; sInT[c4 + 1][row] = v.y;
        sInT[c4 + 2][row] = v.z; sInT[c4 + 3][row] = v.w;
        float4 w = *(const float4*)(W + (size_t)row * 64 + c4);
        sWT[c4 + 0][row] = w.x; sWT[c4 + 1][row] = w.y;
        sWT[c4 + 2][row] = w.z; sWT[c4 + 3][row] = w.w;
    }
    __syncthreads();
    float4 acc0 = make_float4(0.f, 0.f, 0.f, 0.f);
    float4 acc1 = acc0, acc2 = acc0, acc3 = acc0;
#pragma unroll 8
    for (int k = 0; k < 64; k++) {
        float4 a = *(const float4*)(&sInT[k][ty * 4]);
        float4 w = *(const float4*)(&sWT[k][tx * 4]);
        FMA16(acc0, acc1, acc2, acc3, a, w);
    }
    float4 b4 = *(const float4*)(bias + tx * 4);
#pragma unroll
    for (int i = 0; i < 4; i++) {
        int n = n0 + ty * 4 + i;
        if (n < N) {
            float4 v = (i == 0) ? acc0 : (i == 1) ? acc1 : (i == 2) ? acc2 : acc3;
            v.x += b4.x; v.y += b4.y; v.z += b4.z; v.w += b4.w;
            ushort4 o;
            o.x = f2h(v.x); o.y = f2h(v.y); o.z = f2h(v.z); o.w = f2h(v.w);
            *(ushort4*)(out16 + (size_t)n * 64 + tx * 4) = o;
        }
    }
}

// ---------------------------------------------------------------- pool (batch sorted; BN fused; f16 in)
__global__ void k_pool(const unsigned short* __restrict__ h16, const int* __restrict__ batch,
                       const float* __restrict__ aff, float* __restrict__ g, int N) {
    int d = threadIdx.x & 63, r = threadIdx.x >> 6;
    float sc = aff[d], sh = aff[64 + d];
    const _Float16* hp = (const _Float16*)h16;
    int nbase = blockIdx.x * 32;
    float acc = 0.f;
    int gcur = -1;
    for (int i = 0; i < 8; i++) {
        int n = nbase + i * 4 + r;
        if (n < N) {
            int gb = batch[n];
            if (gb != gcur) {
                if (gcur >= 0) atomicAdd(&g[gcur * 64 + d], acc);
                acc = 0.f; gcur = gb;
            }
            acc += fmaf((float)hp[(size_t)n * 64 + d], sc, sh);
        }
    }
    if (gcur >= 0) atomicAdd(&g[gcur * 64 + d], acc);
}

// ---------------------------------------------------------------- head: relu(g@fc1)+fc2
__global__ void k_head(const float* __restrict__ g, const float* __restrict__ fc1W,
                       const float* __restrict__ fc1b, const float* __restrict__ fc2W,
                       const float* __restrict__ fc2b, float* __restrict__ out) {
    __shared__ float sg[64], sg1[64];
    int gi = blockIdx.x, t = threadIdx.x;
    sg[t] = g[gi * 64 + t];
    __syncthreads();
    float a = fc1b[t];
    for (int k = 0; k < 64; k++) a = fmaf(sg[k], fc1W[t * 64 + k], a);
    sg1[t] = fmaxf(a, 0.f);
    __syncthreads();
    if (t < 16) {
        float o = fc2b[t];
        for (int k = 0; k < 64; k++) o = fmaf(sg1[k], fc2W[t * 64 + k], o);
        out[gi * 16 + t] = o;
    }
}

// ---------------------------------------------------------------- launcher
extern "C" void kernel_launch(void* const* d_in, const int* in_sizes, int n_in,
                              void* d_out, int out_size, void* d_ws, size_t ws_size,
                              hipStream_t stream) {
    const float* x       = (const float*)d_in[0];
    const int*   eidx    = (const int*)d_in[1];
    const int*   batch   = (const int*)d_in[2];
    const float* encW    = (const float*)d_in[3];
    const float* encb    = (const float*)d_in[4];
    const float* nnW1    = (const float*)d_in[5];
    const float* nnb1    = (const float*)d_in[6];
    const float* nnW2    = (const float*)d_in[7];
    const float* nnb2    = (const float*)d_in[8];
    const float* mlpW    = (const float*)d_in[9];
    const float* mlpb    = (const float*)d_in[10];
    const float* bnG     = (const float*)d_in[11];
    const float* bnB     = (const float*)d_in[12];
    const float* fc1W    = (const float*)d_in[13];
    const float* fc1b    = (const float*)d_in[14];
    const float* fc2W    = (const float*)d_in[15];
    const float* fc2b    = (const float*)d_in[16];
    float* out = (float*)d_out;

    const int N = in_sizes[0] / 64;
    const int E = in_sizes[1] / 2;
    const int G = 512;
    const int* src = eidx;
    const int* dst = eidx + E;
    const int npp = (N + 7) / 8;  // nodes per XCD partition

    // workspace layout
    char* ws = (char*)d_ws;
    size_t off = 0;
    auto alloc = [&](size_t bytes) { size_t r = off; off = (off + bytes + 255) & ~(size_t)255; return r; };
    int*   deg     = (int*)(ws + alloc((size_t)(N + 1) * 4));
    int*   rowptr  = (int*)(ws + alloc((size_t)(N + 1) * 4));
    int*   bsums   = (int*)(ws + alloc(1024 * 4));
    int*   fill    = (int*)(ws + alloc((size_t)N * 4));
    int*   col     = (int*)(ws + alloc((size_t)E * 4));
    float* cnt     = (float*)(ws + alloc((size_t)N * 4));
    unsigned short* baseF = (unsigned short*)(ws + alloc((size_t)N * 256 * 2 + 131072));  // +pad for OOB tile reads
    unsigned short* hC16 = (unsigned short*)(ws + alloc((size_t)N * 64 * 2 + 32768));     // +pad
    unsigned short* mWF  = (unsigned short*)(ws + alloc((size_t)5 * 64 * 768 * 2));
    unsigned short* nW1F = (unsigned short*)(ws + alloc((size_t)5 * 64 * 64 * 2));
    unsigned short* nW2F = (unsigned short*)(ws + alloc((size_t)5 * 64 * 64 * 2));
    float* bnstats = (float*)(ws + alloc(5 * 128 * 4));
    float* affbuf  = (float*)(ws + alloc(6 * 128 * 4));
    float* gpool   = (float*)(ws + alloc((size_t)G * 64 * 4));

    hipMemsetAsync(deg, 0, (size_t)(N + 1) * 4, stream);
    hipMemsetAsync(fill, 0, (size_t)N * 4, stream);
    hipMemsetAsync(bnstats, 0, 5 * 128 * 4, stream);
    hipMemsetAsync(gpool, 0, (size_t)G * 64 * 4, stream);

    int total = N + 1;
    int nscan = (total + SCAN_B - 1) / SCAN_B;
    int ngrid64 = (N + 63) / 64;
    int ngrid128 = (N + 127) / 128;

    k_degree<<<1024, 256, 0, stream>>>(dst, deg, E, npp);
    k_scan_block<<<nscan, SCAN_B, 0, stream>>>(deg, rowptr, bsums, total);
    k_scan_tops<<<1, SCAN_B, 0, stream>>>(bsums, nscan);
    k_scan_add<<<nscan, SCAN_B, 0, stream>>>(rowptr, bsums, total);
    k_fill<<<1024, 256, 0, stream>>>(src, dst, rowptr, fill, col, E, npp);

    // cast weights to f16
    k_castw<<<240, 256, 0, stream>>>(mlpW, mWF, 61440);
    k_castw<<<20, 256, 0, stream>>>(nnW1, nW1F, 5120);
    k_castw<<<20, 256, 0, stream>>>(nnW2, nW2F, 5120);
    k_ident<<<1, 128, 0, stream>>>(affbuf);

    // encoder: hC16 = f16(x @ encW.T + encb)
    k_gemm64<<<ngrid64, 256, 0, stream>>>(x, encW, encb, hC16, N);

    for (int i = 0; i < 5; i++) {
        const float* aff = affbuf + i * 128;
        k_agg<<<(N + 3) / 4, 256, 0, stream>>>(hC16, rowptr, col, aff, baseF, cnt, N);
        k_mlp<<<ngrid128, 256, 0, stream>>>(baseF, cnt,
                                            mWF + (size_t)i * 64 * 768, mlpb + i * 64,
                                            hC16, aff,
                                            nW1F + (size_t)i * 4096, nnb1 + i * 64,
                                            nW2F + (size_t)i * 4096, nnb2 + i * 64,
                                            bnstats + i * 128, hC16, N);
        k_bnfin<<<1, 64, 0, stream>>>(bnstats + i * 128, bnG + i * 64, bnB + i * 64,
                                      affbuf + (i + 1) * 128, 1.f / (float)N);
    }

    k_pool<<<(N + 31) / 32, 256, 0, stream>>>(hC16, batch, affbuf + 5 * 128, gpool, N);
    k_head<<<G, 64, 0, stream>>>(gpool, fc1W, fc1b, fc2W, fc2b, out);
}

// Round 11
// 905.399 us; speedup vs baseline: 1.3051x; 1.0425x over previous
//
#include <hip/hip_runtime.h>
#include <hip/hip_bf16.h>
#include <hip/hip_fp16.h>

#define DELTA 2.5749f
#define BN_EPS 1e-5f

typedef __attribute__((ext_vector_type(8))) _Float16 f16x8;
typedef __attribute__((ext_vector_type(2))) _Float16 f16x2;
typedef __attribute__((ext_vector_type(4))) float f32x4;

__device__ inline unsigned short f2h(float f) {
    union { _Float16 h; unsigned short u; } v;
    v.h = (_Float16)f;  // RNE
    return v.u;
}

__device__ inline int pkmax(int a, int b) {
    f16x2 x = __builtin_bit_cast(f16x2, a);
    f16x2 y = __builtin_bit_cast(f16x2, b);
    f16x2 r = __builtin_elementwise_max(x, y);  // v_pk_max_f16
    return __builtin_bit_cast(int, r);
}

// ---------------------------------------------------------------- CSR build (XCD-partitioned)
__global__ __launch_bounds__(256) void k_degree(const int* __restrict__ dst,
                                                int* __restrict__ deg, int E, int npp) {
    int part = blockIdx.x & 7;
    int lo = part * npp, hi = lo + npp;
    int stride = (gridDim.x >> 3) * 256;
    for (int e = (blockIdx.x >> 3) * 256 + threadIdx.x; e < E; e += stride) {
        int d = dst[e];
        if (d >= lo && d < hi) atomicAdd(&deg[d], 1);
    }
}

#define SCAN_B 1024
__global__ void k_scan_block(const int* __restrict__ deg, int* __restrict__ excl,
                             int* __restrict__ bsums, int total) {
    __shared__ int s[SCAN_B];
    int t = threadIdx.x, i = blockIdx.x * SCAN_B + t;
    int v = (i < total) ? deg[i] : 0;
    s[t] = v; __syncthreads();
    for (int off = 1; off < SCAN_B; off <<= 1) {
        int x = (t >= off) ? s[t - off] : 0;
        __syncthreads();
        s[t] += x;
        __syncthreads();
    }
    if (i < total) excl[i] = s[t] - v;
    if (t == SCAN_B - 1) bsums[blockIdx.x] = s[t];
}

__global__ void k_scan_tops(int* __restrict__ bsums, int nb) {
    __shared__ int s[SCAN_B];
    int t = threadIdx.x;
    int v = (t < nb) ? bsums[t] : 0;
    s[t] = v; __syncthreads();
    for (int off = 1; off < SCAN_B; off <<= 1) {
        int x = (t >= off) ? s[t - off] : 0;
        __syncthreads();
        s[t] += x;
        __syncthreads();
    }
    if (t < nb) bsums[t] = s[t] - v;  // exclusive
}

__global__ void k_scan_add(int* __restrict__ excl, const int* __restrict__ bsums, int total) {
    int i = blockIdx.x * SCAN_B + threadIdx.x;
    if (i < total) excl[i] += bsums[blockIdx.x];
}

__global__ __launch_bounds__(256) void k_fill(const int* __restrict__ src,
                                              const int* __restrict__ dst,
                                              const int* __restrict__ rowptr,
                                              int* __restrict__ fill,
                                              int* __restrict__ col, int E, int npp) {
    int part = blockIdx.x & 7;
    int lo = part * npp, hi = lo + npp;
    int stride = (gridDim.x >> 3) * 256;
    for (int e = (blockIdx.x >> 3) * 256 + threadIdx.x; e < E; e += stride) {
        int d = dst[e];
        if (d >= lo && d < hi) {
            int pos = rowptr[d] + atomicAdd(&fill[d], 1);
            col[pos] = src[e];
        }
    }
}

// ---------------------------------------------------------------- weight cast f32 -> f16
__global__ void k_castw(const float* __restrict__ w, unsigned short* __restrict__ o, int n4) {
    int i = blockIdx.x * 256 + threadIdx.x;
    if (i < n4) {
        float4 v = ((const float4*)w)[i];
        ushort4 r;
        r.x = f2h(v.x); r.y = f2h(v.y); r.z = f2h(v.z); r.w = f2h(v.w);
        ((ushort4*)o)[i] = r;
    }
}

// ---------------------------------------------------------------- BN affine helpers
__global__ void k_ident(float* __restrict__ aff) {
    int t = threadIdx.x;  // 128
    aff[t] = (t < 64) ? 1.f : 0.f;
}

__global__ void k_bnfin(const float* __restrict__ stat, const float* __restrict__ gamma,
                        const float* __restrict__ beta, float* __restrict__ aff, float invN) {
    int d = threadIdx.x;  // 64
    float mu = stat[d] * invN;
    float var = stat[64 + d] * invN - mu * mu;
    float sc = rsqrtf(var + BN_EPS) * gamma[d];
    aff[d] = sc;
    aff[64 + d] = beta[d] - mu * sc;
}

// ---------------------------------------------------------------- aggregation
// 8 lanes/edge (f16x8 = 16B), 8 edges in flight, unroll 2. RAW aggregation:
// BN affine applied analytically in epilogue (var'=sc^2*var; shift cancels).
// Requires sc>0 for the max identity (true here: gamma=1).
__global__ __launch_bounds__(256) void k_agg(const unsigned short* __restrict__ h16,
                                             const int* __restrict__ rowptr,
                                             const int* __restrict__ col,
                                             const float* __restrict__ aff,
                                             unsigned short* __restrict__ baseF,
                                             float* __restrict__ cnt, int N) {
    int node = blockIdx.x * 4 + (threadIdx.x >> 6);
    int lane = threadIdx.x & 63;
    if (node >= N) return;
    int slot = lane >> 3;        // 8 concurrent edges
    int fo = (lane & 7) * 8;     // 8 features per lane
    const _Float16* hp = (const _Float16*)h16;
    int s0 = rowptr[node], s1 = rowptr[node + 1];
    int deg = s1 - s0;
    float sf[8], qf[8];
#pragma unroll
    for (int j = 0; j < 8; j++) { sf[j] = 0.f; qf[j] = 0.f; }
    f16x8 mxv;
#pragma unroll
    for (int j = 0; j < 8; j++) mxv[j] = (_Float16)(-65504.0f);

    int e = s0 + slot;
    for (; e + 8 < s1; e += 16) {
        int sA = col[e], sB = col[e + 8];
        f16x8 v1 = *(const f16x8*)(hp + (size_t)sA * 64 + fo);
        f16x8 v2 = *(const f16x8*)(hp + (size_t)sB * 64 + fo);
        mxv = __builtin_elementwise_max(mxv, v1);
        mxv = __builtin_elementwise_max(mxv, v2);
#pragma unroll
        for (int j = 0; j < 8; j++) {
            float x1 = (float)v1[j];
            float x2 = (float)v2[j];
            sf[j] += x1;
            qf[j] = fmaf(x1, x1, qf[j]);  // v_fma_mix candidate
            sf[j] += x2;
            qf[j] = fmaf(x2, x2, qf[j]);
        }
    }
    if (e < s1) {
        int s = col[e];
        f16x8 v = *(const f16x8*)(hp + (size_t)s * 64 + fo);
        mxv = __builtin_elementwise_max(mxv, v);
#pragma unroll
        for (int j = 0; j < 8; j++) {
            float x = (float)v[j];
            sf[j] += x;
            qf[j] = fmaf(x, x, qf[j]);
        }
    }
    // butterfly reduce across the 8 slots (lane xor 8, 16, 32)
    union { f16x8 h; int i[4]; } mu;
    mu.h = mxv;
#pragma unroll
    for (int m = 8; m <= 32; m <<= 1) {
#pragma unroll
        for (int j = 0; j < 8; j++) {
            sf[j] += __shfl_xor(sf[j], m);
            qf[j] += __shfl_xor(qf[j], m);
        }
#pragma unroll
        for (int d = 0; d < 4; d++) mu.i[d] = pkmax(mu.i[d], __shfl_xor(mu.i[d], m));
    }
    float c = (float)(deg > 0 ? deg : 1);
    float ic = 1.f / c;
    if (slot < 4) {
        float4 aL = *(const float4*)(aff + fo);
        float4 aH = *(const float4*)(aff + fo + 4);
        float4 bL = *(const float4*)(aff + 64 + fo);
        float4 bH = *(const float4*)(aff + 64 + fo + 4);
        float sc[8] = {aL.x, aL.y, aL.z, aL.w, aH.x, aH.y, aH.z, aH.w};
        float sh[8] = {bL.x, bL.y, bL.z, bL.w, bH.x, bH.y, bH.z, bH.w};
        float w[8];
        if (deg == 0) {
#pragma unroll
            for (int j = 0; j < 8; j++) w[j] = 0.f;
        } else if (slot == 0) {       // sum' = sc*sum + c*sh
#pragma unroll
            for (int j = 0; j < 8; j++) w[j] = fmaf(sc[j], sf[j], c * sh[j]);
        } else if (slot == 1) {       // max' = sc*max + sh   (sc > 0)
#pragma unroll
            for (int j = 0; j < 8; j++) w[j] = fmaf(sc[j], (float)mu.h[j], sh[j]);
        } else if (slot == 2) {       // mean' = sc*mean + sh
#pragma unroll
            for (int j = 0; j < 8; j++) w[j] = fmaf(sc[j], sf[j] * ic, sh[j]);
        } else {                      // var' = sc^2 * relu(sq/c - mean^2)
#pragma unroll
            for (int j = 0; j < 8; j++) {
                float mn = sf[j] * ic;
                w[j] = sc[j] * sc[j] * fmaxf(fmaf(-mn, mn, qf[j] * ic), 0.f);
            }
        }
        f16x8 hv;
#pragma unroll
        for (int j = 0; j < 8; j++) hv[j] = (_Float16)w[j];
        *(f16x8*)(baseF + (size_t)node * 256 + slot * 64 + fo) = hv;
    }
    if (lane == 0) cnt[node] = c;
}

// ---------------------------------------------------------------- fused per-layer MLP
// Phase0: PNA triple GEMM (f16 MFMA, K=256, weights LDS-staged per 64-k chunk)
// Phase1: +bias +scalers +BN-affine residual -> bufA (f16, LDS)
// Phase2: nn1 GEMM (f16 MFMA from bufA) + relu -> bufB
// Phase3: nn2 GEMM + relu -> bufA + bnstat partials
// Phase4: coalesced hOut16 store + bnstat reduce. Block = 256 thr / 128 nodes.
__global__ __launch_bounds__(256) void k_mlp(const unsigned short* __restrict__ baseF,
                                             const float* __restrict__ cnt,
                                             const unsigned short* __restrict__ mWF,
                                             const float* __restrict__ mb,
                                             const unsigned short* __restrict__ hres16,
                                             const float* __restrict__ aff,
                                             const unsigned short* __restrict__ w1F,
                                             const float* __restrict__ b1,
                                             const unsigned short* __restrict__ w2F,
                                             const float* __restrict__ b2,
                                             float* __restrict__ bnstat,
                                             unsigned short* __restrict__ hOut16, int N) {
    __shared__ char smem[61440];
    _Float16* ldsW = (_Float16*)smem;             // 24 KB (reused as `red` later)
    _Float16* bufA = (_Float16*)(smem + 24576);   // [128][72] f16
    _Float16* bufB = bufA + 128 * 72;             // [128][72] f16
    float* red = (float*)smem;                    // 8 KB reuse of ldsW region

    int t = threadIdx.x;
    int wave = t >> 6, lane = t & 63;
    int r16 = lane & 15, quad = lane >> 4;
    int n0 = blockIdx.x * 128;
    int m0 = n0 + wave * 32;

    // ---------------- Phase 0: base[N,256] x 3 matrices
    const _Float16* aptr0 = (const _Float16*)baseF + (size_t)(m0 + r16) * 256 + quad * 8;
    const _Float16* aptr1 = aptr0 + 16 * 256;
    f32x4 acc0[12], acc1[12];
#pragma unroll
    for (int i = 0; i < 12; i++) {
        acc0[i] = (f32x4){0.f, 0.f, 0.f, 0.f};
        acc1[i] = (f32x4){0.f, 0.f, 0.f, 0.f};
    }
    f16x8 a00 = *(const f16x8*)(aptr0 + 0);
    f16x8 a01 = *(const f16x8*)(aptr1 + 0);
    f16x8 a10 = *(const f16x8*)(aptr0 + 32);
    f16x8 a11 = *(const f16x8*)(aptr1 + 32);

#pragma unroll 1
    for (int chunk = 0; chunk < 4; chunk++) {
        if (chunk) __syncthreads();
#pragma unroll
        for (int rb = 0; rb < 24; rb += 4) {
            int rec = rb + wave;
            int s = rec / 12, tile = rec % 12;
            int mat = tile >> 2, nt = tile & 3;
            uint4 v = *(const uint4*)(mWF + (size_t)(nt * 16 + r16) * 768 + mat * 256
                                      + chunk * 64 + s * 32 + quad * 8);
            *(uint4*)((unsigned short*)ldsW + rec * 512 + lane * 8) = v;
        }
        __syncthreads();
        f16x8 n00, n01, n10, n11;
        if (chunk < 3) {
            int ko = (chunk + 1) * 64;
            n00 = *(const f16x8*)(aptr0 + ko);
            n01 = *(const f16x8*)(aptr1 + ko);
            n10 = *(const f16x8*)(aptr0 + ko + 32);
            n11 = *(const f16x8*)(aptr1 + ko + 32);
        }
#pragma unroll
        for (int s = 0; s < 2; s++) {
            f16x8 af0 = s ? a10 : a00;
            f16x8 af1 = s ? a11 : a01;
#pragma unroll
            for (int tile = 0; tile < 12; tile++) {
                f16x8 wF = *(const f16x8*)(ldsW + (s * 12 + tile) * 512 + lane * 8);
                acc0[tile] = __builtin_amdgcn_mfma_f32_16x16x32_f16(af0, wF, acc0[tile], 0, 0, 0);
                acc1[tile] = __builtin_amdgcn_mfma_f32_16x16x32_f16(af1, wF, acc1[tile], 0, 0, 0);
            }
        }
        a00 = n00; a01 = n01; a10 = n10; a11 = n11;
    }
    __syncthreads();

    // ---------------- Phase 1a: residual copy into bufA (coalesced)
    {
        int nl = t >> 1, fo = (t & 1) * 32;
        int gn = n0 + nl;
        uint4* dp = (uint4*)(bufA + nl * 72 + fo);
        if (gn < N) {
            const uint4* sp = (const uint4*)(hres16 + (size_t)gn * 64 + fo);
            dp[0] = sp[0]; dp[1] = sp[1]; dp[2] = sp[2]; dp[3] = sp[3];
        } else {
            uint4 z = make_uint4(0, 0, 0, 0);
            dp[0] = z; dp[1] = z; dp[2] = z; dp[3] = z;
        }
    }
    __syncthreads();

    // ---------------- Phase 1b: combine accs + bias + scalers + affine residual
    float scf[4], shf[4], mbv[4];
#pragma unroll
    for (int nt = 0; nt < 4; nt++) {
        int f = nt * 16 + r16;
        scf[nt] = aff[f]; shf[nt] = aff[64 + f]; mbv[nt] = mb[f];
    }
#pragma unroll
    for (int mt = 0; mt < 2; mt++) {
#pragma unroll
        for (int i = 0; i < 4; i++) {
            int nl = wave * 32 + mt * 16 + quad * 4 + i;
            int gn = n0 + nl;
            if (gn < N) {
                float c = cnt[gn];
                float amp = c / DELTA, att = DELTA / c;
                f32x4* a = mt ? acc1 : acc0;
#pragma unroll
                for (int nt = 0; nt < 4; nt++) {
                    int f = nt * 16 + r16;
                    float r = (float)bufA[nl * 72 + f];
                    float v = a[nt][i] + amp * a[4 + nt][i] + att * a[8 + nt][i]
                            + mbv[nt] + fmaf(r, scf[nt], shf[nt]);
                    bufA[nl * 72 + f] = (_Float16)v;
                }
            }
        }
    }
    __syncthreads();

    // ---------------- Phase 2: nn1 (relu(t @ W1 + b1)) -> bufB
    f32x4 accN[8];
#pragma unroll
    for (int i = 0; i < 8; i++) accN[i] = (f32x4){0.f, 0.f, 0.f, 0.f};
#pragma unroll
    for (int s = 0; s < 2; s++) {
        f16x8 fA0 = *(const f16x8*)(bufA + (wave * 32 + r16) * 72 + s * 32 + quad * 8);
        f16x8 fA1 = *(const f16x8*)(bufA + (wave * 32 + 16 + r16) * 72 + s * 32 + quad * 8);
#pragma unroll
        for (int nt = 0; nt < 4; nt++) {
            f16x8 wB = *(const f16x8*)((const _Float16*)w1F + (size_t)(nt * 16 + r16) * 64
                                       + s * 32 + quad * 8);
            accN[nt]     = __builtin_amdgcn_mfma_f32_16x16x32_f16(fA0, wB, accN[nt], 0, 0, 0);
            accN[4 + nt] = __builtin_amdgcn_mfma_f32_16x16x32_f16(fA1, wB, accN[4 + nt], 0, 0, 0);
        }
    }
    float b1v[4];
#pragma unroll
    for (int nt = 0; nt < 4; nt++) b1v[nt] = b1[nt * 16 + r16];
#pragma unroll
    for (int mt = 0; mt < 2; mt++) {
#pragma unroll
        for (int i = 0; i < 4; i++) {
            int nl = wave * 32 + mt * 16 + quad * 4 + i;
#pragma unroll
            for (int nt = 0; nt < 4; nt++) {
                float v = fmaxf(accN[mt * 4 + nt][i] + b1v[nt], 0.f);
                bufB[nl * 72 + nt * 16 + r16] = (_Float16)v;
            }
        }
    }
    __syncthreads();

    // ---------------- Phase 3: nn2 (relu(u @ W2 + b2)) -> bufA + bnstat partials
    f32x4 accM[8];
#pragma unroll
    for (int i = 0; i < 8; i++) accM[i] = (f32x4){0.f, 0.f, 0.f, 0.f};
#pragma unroll
    for (int s = 0; s < 2; s++) {
        f16x8 fA0 = *(const f16x8*)(bufB + (wave * 32 + r16) * 72 + s * 32 + quad * 8);
        f16x8 fA1 = *(const f16x8*)(bufB + (wave * 32 + 16 + r16) * 72 + s * 32 + quad * 8);
#pragma unroll
        for (int nt = 0; nt < 4; nt++) {
            f16x8 wB = *(const f16x8*)((const _Float16*)w2F + (size_t)(nt * 16 + r16) * 64
                                       + s * 32 + quad * 8);
            accM[nt]     = __builtin_amdgcn_mfma_f32_16x16x32_f16(fA0, wB, accM[nt], 0, 0, 0);
            accM[4 + nt] = __builtin_amdgcn_mfma_f32_16x16x32_f16(fA1, wB, accM[4 + nt], 0, 0, 0);
        }
    }
    float b2v[4], s1[4], s2[4];
#pragma unroll
    for (int nt = 0; nt < 4; nt++) {
        b2v[nt] = b2[nt * 16 + r16]; s1[nt] = 0.f; s2[nt] = 0.f;
    }
#pragma unroll
    for (int mt = 0; mt < 2; mt++) {
#pragma unroll
        for (int i = 0; i < 4; i++) {
            int nl = wave * 32 + mt * 16 + quad * 4 + i;
            bool ok = (n0 + nl) < N;
#pragma unroll
            for (int nt = 0; nt < 4; nt++) {
                float v = fmaxf(accM[mt * 4 + nt][i] + b2v[nt], 0.f);
                if (ok) { s1[nt] += v; s2[nt] = fmaf(v, v, s2[nt]); }
                bufA[nl * 72 + nt * 16 + r16] = (_Float16)v;
            }
        }
    }
#pragma unroll
    for (int nt = 0; nt < 4; nt++) {
        int row = wave * 4 + quad;
        red[row * 64 + nt * 16 + r16] = s1[nt];
        red[1024 + row * 64 + nt * 16 + r16] = s2[nt];
    }
    __syncthreads();

    // ---------------- Phase 4: coalesced store + bnstat reduce
    {
        int nl = t >> 1, fo = (t & 1) * 32;
        int gn = n0 + nl;
        if (gn < N) {
            const uint4* sp = (const uint4*)(bufA + nl * 72 + fo);
            uint4* dp = (uint4*)(hOut16 + (size_t)gn * 64 + fo);
            dp[0] = sp[0]; dp[1] = sp[1]; dp[2] = sp[2]; dp[3] = sp[3];
        }
    }
    if (t < 128) {
        int d = t & 63, part = t >> 6;
        float tot = 0.f;
#pragma unroll
        for (int r = 0; r < 16; r++) tot += red[part * 1024 + r * 64 + d];
        atomicAdd(&bnstat[part * 64 + d], tot);
    }
}

// ---------------------------------------------------------------- 64x64 GEMM (encoder only)
#define FMA16(ACC0, ACC1, ACC2, ACC3, A, W)                                \
    do {                                                                   \
        ACC0.x = fmaf(A.x, W.x, ACC0.x); ACC0.y = fmaf(A.x, W.y, ACC0.y);  \
        ACC0.z = fmaf(A.x, W.z, ACC0.z); ACC0.w = fmaf(A.x, W.w, ACC0.w);  \
        ACC1.x = fmaf(A.y, W.x, ACC1.x); ACC1.y = fmaf(A.y, W.y, ACC1.y);  \
        ACC1.z = fmaf(A.y, W.z, ACC1.z); ACC1.w = fmaf(A.y, W.w, ACC1.w);  \
        ACC2.x = fmaf(A.z, W.x, ACC2.x); ACC2.y = fmaf(A.z, W.y, ACC2.y);  \
        ACC2.z = fmaf(A.z, W.z, ACC2.z); ACC2.w = fmaf(A.z, W.w, ACC2.w);  \
        ACC3.x = fmaf(A.w, W.x, ACC3.x); ACC3.y = fmaf(A.w, W.y, ACC3.y);  \
        ACC3.z = fmaf(A.w, W.z, ACC3.z); ACC3.w = fmaf(A.w, W.w, ACC3.w);  \
    } while (0)

__global__ __launch_bounds__(256) void k_gemm64(const float* __restrict__ in,
                                                const float* __restrict__ W,
                                                const float* __restrict__ bias,
                                                unsigned short* __restrict__ out16, int N) {
    __shared__ float sInT[64][64];  // [k][node]
    __shared__ float sWT[64][64];   // [k][feat]
    int t = threadIdx.x;
    int tx = t & 15, ty = t >> 4;
    int n0 = blockIdx.x * 64;
    int c4 = tx * 4;
#pragma unroll
    for (int ch = 0; ch < 4; ch++) {
        int row = ch * 16 + ty;
        float4 v = make_float4(0.f, 0.f, 0.f, 0.f);
        if (n0 + row < N) v = *(const float4*)(in + (size_t)(n0 + row) * 64 + c4);
        sInT[c4 + 0][row] = v.x; sInT[c4 + 1][row] = v.y;
        sInT[c4 + 2][row] = v.z; sInT[c4 + 3][row] = v.w;
        float4 w = *(const float4*)(W + (size_t)row * 64 + c4);
        sWT[c4 + 0][row] = w.x; sWT[c4 + 1][row] = w.y;
        sWT[c4 + 2][row] = w.z; sWT[c4 + 3][row] = w.w;
    }
    __syncthreads();
    float4 acc0 = make_float4(0.f, 0.f, 0.f, 0.f);
    float4 acc1 = acc0, acc2 = acc0, acc3 = acc0;
#pragma unroll 8
    for (int k = 0; k < 64; k++) {
        float4 a = *(const float4*)(&sInT[k][ty * 4]);
        float4 w = *(const float4*)(&sWT[k][tx * 4]);
        FMA16(acc0, acc1, acc2, acc3, a, w);
    }
    float4 b4 = *(const float4*)(bias + tx * 4);
#pragma unroll
    for (int i = 0; i < 4; i++) {
        int n = n0 + ty * 4 + i;
        if (n < N) {
            float4 v = (i == 0) ? acc0 : (i == 1) ? acc1 : (i == 2) ? acc2 : acc3;
            v.x += b4.x; v.y += b4.y; v.z += b4.z; v.w += b4.w;
            ushort4 o;
            o.x = f2h(v.x); o.y = f2h(v.y); o.z = f2h(v.z); o.w = f2h(v.w);
            *(ushort4*)(out16 + (size_t)n * 64 + tx * 4) = o;
        }
    }
}

// ---------------------------------------------------------------- pool (batch sorted; BN fused; f16 in)
__global__ void k_pool(const unsigned short* __restrict__ h16, const int* __restrict__ batch,
                       const float* __restrict__ aff, float* __restrict__ g, int N) {
    int d = threadIdx.x & 63, r = threadIdx.x >> 6;
    float sc = aff[d], sh = aff[64 + d];
    const _Float16* hp = (const _Float16*)h16;
    int nbase = blockIdx.x * 32;
    float acc = 0.f;
    int gcur = -1;
    for (int i = 0; i < 8; i++) {
        int n = nbase + i * 4 + r;
        if (n < N) {
            int gb = batch[n];
            if (gb != gcur) {
                if (gcur >= 0) atomicAdd(&g[gcur * 64 + d], acc);
                acc = 0.f; gcur = gb;
            }
            acc += fmaf((float)hp[(size_t)n * 64 + d], sc, sh);
        }
    }
    if (gcur >= 0) atomicAdd(&g[gcur * 64 + d], acc);
}

// ---------------------------------------------------------------- head: relu(g@fc1)+fc2
__global__ void k_head(const float* __restrict__ g, const float* __restrict__ fc1W,
                       const float* __restrict__ fc1b, const float* __restrict__ fc2W,
                       const float* __restrict__ fc2b, float* __restrict__ out) {
    __shared__ float sg[64], sg1[64];
    int gi = blockIdx.x, t = threadIdx.x;
    sg[t] = g[gi * 64 + t];
    __syncthreads();
    float a = fc1b[t];
    for (int k = 0; k < 64; k++) a = fmaf(sg[k], fc1W[t * 64 + k], a);
    sg1[t] = fmaxf(a, 0.f);
    __syncthreads();
    if (t < 16) {
        float o = fc2b[t];
        for (int k = 0; k < 64; k++) o = fmaf(sg1[k], fc2W[t * 64 + k], o);
        out[gi * 16 + t] = o;
    }
}

// ---------------------------------------------------------------- launcher
extern "C" void kernel_launch(void* const* d_in, const int* in_sizes, int n_in,
                              void* d_out, int out_size, void* d_ws, size_t ws_size,
                              hipStream_t stream) {
    const float* x       = (const float*)d_in[0];
    const int*   eidx    = (const int*)d_in[1];
    const int*   batch   = (const int*)d_in[2];
    const float* encW    = (const float*)d_in[3];
    const float* encb    = (const float*)d_in[4];
    const float* nnW1    = (const float*)d_in[5];
    const float* nnb1    = (const float*)d_in[6];
    const float* nnW2    = (const float*)d_in[7];
    const float* nnb2    = (const float*)d_in[8];
    const float* mlpW    = (const float*)d_in[9];
    const float* mlpb    = (const float*)d_in[10];
    const float* bnG     = (const float*)d_in[11];
    const float* bnB     = (const float*)d_in[12];
    const float* fc1W    = (const float*)d_in[13];
    const float* fc1b    = (const float*)d_in[14];
    const float* fc2W    = (const float*)d_in[15];
    const float* fc2b    = (const float*)d_in[16];
    float* out = (float*)d_out;

    const int N = in_sizes[0] / 64;
    const int E = in_sizes[1] / 2;
    const int G = 512;
    const int* src = eidx;
    const int* dst = eidx + E;
    const int npp = (N + 7) / 8;  // nodes per XCD partition

    // workspace layout
    char* ws = (char*)d_ws;
    size_t off = 0;
    auto alloc = [&](size_t bytes) { size_t r = off; off = (off + bytes + 255) & ~(size_t)255; return r; };
    int*   deg     = (int*)(ws + alloc((size_t)(N + 1) * 4));
    int*   rowptr  = (int*)(ws + alloc((size_t)(N + 1) * 4));
    int*   bsums   = (int*)(ws + alloc(1024 * 4));
    int*   fill    = (int*)(ws + alloc((size_t)N * 4));
    int*   col     = (int*)(ws + alloc((size_t)E * 4));
    float* cnt     = (float*)(ws + alloc((size_t)N * 4));
    unsigned short* baseF = (unsigned short*)(ws + alloc((size_t)N * 256 * 2 + 131072));  // +pad for OOB tile reads
    unsigned short* hC16 = (unsigned short*)(ws + alloc((size_t)N * 64 * 2 + 32768));     // +pad
    unsigned short* mWF  = (unsigned short*)(ws + alloc((size_t)5 * 64 * 768 * 2));
    unsigned short* nW1F = (unsigned short*)(ws + alloc((size_t)5 * 64 * 64 * 2));
    unsigned short* nW2F = (unsigned short*)(ws + alloc((size_t)5 * 64 * 64 * 2));
    float* bnstats = (float*)(ws + alloc(5 * 128 * 4));
    float* affbuf  = (float*)(ws + alloc(6 * 128 * 4));
    float* gpool   = (float*)(ws + alloc((size_t)G * 64 * 4));

    hipMemsetAsync(deg, 0, (size_t)(N + 1) * 4, stream);
    hipMemsetAsync(fill, 0, (size_t)N * 4, stream);
    hipMemsetAsync(bnstats, 0, 5 * 128 * 4, stream);
    hipMemsetAsync(gpool, 0, (size_t)G * 64 * 4, stream);

    int total = N + 1;
    int nscan = (total + SCAN_B - 1) / SCAN_B;
    int ngrid64 = (N + 63) / 64;
    int ngrid128 = (N + 127) / 128;

    k_degree<<<1024, 256, 0, stream>>>(dst, deg, E, npp);
    k_scan_block<<<nscan, SCAN_B, 0, stream>>>(deg, rowptr, bsums, total);
    k_scan_tops<<<1, SCAN_B, 0, stream>>>(bsums, nscan);
    k_scan_add<<<nscan, SCAN_B, 0, stream>>>(rowptr, bsums, total);
    k_fill<<<1024, 256, 0, stream>>>(src, dst, rowptr, fill, col, E, npp);

    // cast weights to f16
    k_castw<<<240, 256, 0, stream>>>(mlpW, mWF, 61440);
    k_castw<<<20, 256, 0, stream>>>(nnW1, nW1F, 5120);
    k_castw<<<20, 256, 0, stream>>>(nnW2, nW2F, 5120);
    k_ident<<<1, 128, 0, stream>>>(affbuf);

    // encoder: hC16 = f16(x @ encW.T + encb)
    k_gemm64<<<ngrid64, 256, 0, stream>>>(x, encW, encb, hC16, N);

    for (int i = 0; i < 5; i++) {
        const float* aff = affbuf + i * 128;
        k_agg<<<(N + 3) / 4, 256, 0, stream>>>(hC16, rowptr, col, aff, baseF, cnt, N);
        k_mlp<<<ngrid128, 256, 0, stream>>>(baseF, cnt,
                                            mWF + (size_t)i * 64 * 768, mlpb + i * 64,
                                            hC16, aff,
                                            nW1F + (size_t)i * 4096, nnb1 + i * 64,
                                            nW2F + (size_t)i * 4096, nnb2 + i * 64,
                                            bnstats + i * 128, hC16, N);
        k_bnfin<<<1, 64, 0, stream>>>(bnstats + i * 128, bnG + i * 64, bnB + i * 64,
                                      affbuf + (i + 1) * 128, 1.f / (float)N);
    }

    k_pool<<<(N + 31) / 32, 256, 0, stream>>>(hC16, batch, affbuf + 5 * 128, gpool, N);
    k_head<<<G, 64, 0, stream>>>(gpool, fc1W, fc1b, fc2W, fc2b, out);
}

// Round 12
// 787.919 us; speedup vs baseline: 1.4997x; 1.1491x over previous
//
#include <hip/hip_runtime.h>
#include <hip/hip_bf16.h>
#include <hip/hip_fp16.h>

#define DELTA 2.5749f
#define BN_EPS 1e-5f

typedef __attribute__((ext_vector_type(8))) _Float16 f16x8;
typedef __attribute__((ext_vector_type(2))) _Float16 f16x2;
typedef __attribute__((ext_vector_type(4))) float f32x4;

__device__ inline unsigned short f2h(float f) {
    union { _Float16 h; unsigned short u; } v;
    v.h = (_Float16)f;  // RNE
    return v.u;
}

// ---------------------------------------------------------------- CSR build (XCD-partitioned)
__global__ __launch_bounds__(256) void k_degree(const int* __restrict__ dst,
                                                int* __restrict__ deg, int E, int npp) {
    int part = blockIdx.x & 7;
    int lo = part * npp, hi = lo + npp;
    int stride = (gridDim.x >> 3) * 256;
    for (int e = (blockIdx.x >> 3) * 256 + threadIdx.x; e < E; e += stride) {
        int d = dst[e];
        if (d >= lo && d < hi) atomicAdd(&deg[d], 1);
    }
}

#define SCAN_B 1024
__global__ void k_scan_block(const int* __restrict__ deg, int* __restrict__ excl,
                             int* __restrict__ bsums, int total) {
    __shared__ int s[SCAN_B];
    int t = threadIdx.x, i = blockIdx.x * SCAN_B + t;
    int v = (i < total) ? deg[i] : 0;
    s[t] = v; __syncthreads();
    for (int off = 1; off < SCAN_B; off <<= 1) {
        int x = (t >= off) ? s[t - off] : 0;
        __syncthreads();
        s[t] += x;
        __syncthreads();
    }
    if (i < total) excl[i] = s[t] - v;
    if (t == SCAN_B - 1) bsums[blockIdx.x] = s[t];
}

__global__ void k_scan_tops(int* __restrict__ bsums, int nb) {
    __shared__ int s[SCAN_B];
    int t = threadIdx.x;
    int v = (t < nb) ? bsums[t] : 0;
    s[t] = v; __syncthreads();
    for (int off = 1; off < SCAN_B; off <<= 1) {
        int x = (t >= off) ? s[t - off] : 0;
        __syncthreads();
        s[t] += x;
        __syncthreads();
    }
    if (t < nb) bsums[t] = s[t] - v;  // exclusive
}

__global__ void k_scan_add(int* __restrict__ excl, const int* __restrict__ bsums, int total) {
    int i = blockIdx.x * SCAN_B + threadIdx.x;
    if (i < total) excl[i] += bsums[blockIdx.x];
}

__global__ __launch_bounds__(256) void k_fill(const int* __restrict__ src,
                                              const int* __restrict__ dst,
                                              const int* __restrict__ rowptr,
                                              int* __restrict__ fill,
                                              int* __restrict__ col, int E, int npp) {
    int part = blockIdx.x & 7;
    int lo = part * npp, hi = lo + npp;
    int stride = (gridDim.x >> 3) * 256;
    for (int e = (blockIdx.x >> 3) * 256 + threadIdx.x; e < E; e += stride) {
        int d = dst[e];
        if (d >= lo && d < hi) {
            int pos = rowptr[d] + atomicAdd(&fill[d], 1);
            col[pos] = src[e];
        }
    }
}

// ---------------------------------------------------------------- weight cast f32 -> f16
__global__ void k_castw(const float* __restrict__ w, unsigned short* __restrict__ o, int n4) {
    int i = blockIdx.x * 256 + threadIdx.x;
    if (i < n4) {
        float4 v = ((const float4*)w)[i];
        ushort4 r;
        r.x = f2h(v.x); r.y = f2h(v.y); r.z = f2h(v.z); r.w = f2h(v.w);
        ((ushort4*)o)[i] = r;
    }
}

// ---------------------------------------------------------------- BN affine helpers
__global__ void k_ident(float* __restrict__ aff) {
    int t = threadIdx.x;  // 128
    aff[t] = (t < 64) ? 1.f : 0.f;
}

__global__ void k_bnfin(const float* __restrict__ stat, const float* __restrict__ gamma,
                        const float* __restrict__ beta, float* __restrict__ aff, float invN) {
    int d = threadIdx.x;  // 64
    float mu = stat[d] * invN;
    float var = stat[64 + d] * invN - mu * mu;
    float sc = rsqrtf(var + BN_EPS) * gamma[d];
    aff[d] = sc;
    aff[64 + d] = beta[d] - mu * sc;
}

// ---------------------------------------------------------------- aggregation
// 2 nodes per wave (half-wave each); lane owns an f16x2 feature pair across ALL
// edges of its node -> NO cross-lane reduction (the old butterfly was ~60
// ds_bpermute/node = the bottleneck). Serial edge loop unrolled x4 for MLP.
// BN affine applied analytically in epilogue (sc>0 holds: gamma=1).
#define ACC2(V)                                                            \
    do {                                                                   \
        mx = __builtin_elementwise_max(mx, V);                             \
        float x0 = (float)V[0], x1 = (float)V[1];                          \
        sa += x0; qa = fmaf(x0, x0, qa);                                   \
        sb += x1; qb = fmaf(x1, x1, qb);                                   \
    } while (0)

__global__ __launch_bounds__(256) void k_agg(const unsigned short* __restrict__ h16,
                                             const int* __restrict__ rowptr,
                                             const int* __restrict__ col,
                                             const float* __restrict__ aff,
                                             unsigned short* __restrict__ baseF,
                                             float* __restrict__ cnt, int N) {
    int t = threadIdx.x;
    int lane = t & 63;
    int half = lane >> 5;          // which node of the wave's pair
    int fl = lane & 31;            // feature-pair index (feats fl*2, fl*2+1)
    int node = blockIdx.x * 8 + (t >> 6) * 2 + half;
    if (node >= N) return;
    const _Float16* hp = (const _Float16*)h16;
    int s0 = rowptr[node], s1 = rowptr[node + 1];
    int deg = s1 - s0;
    float sa = 0.f, sb = 0.f, qa = 0.f, qb = 0.f;
    f16x2 mx;
    mx[0] = (_Float16)(-65504.0f); mx[1] = (_Float16)(-65504.0f);
    int fo2 = fl * 2;
    int e = s0;
    for (; e + 3 < s1; e += 4) {
        int c0 = col[e], c1 = col[e + 1], c2 = col[e + 2], c3 = col[e + 3];
        f16x2 v0 = *(const f16x2*)(hp + (size_t)c0 * 64 + fo2);
        f16x2 v1 = *(const f16x2*)(hp + (size_t)c1 * 64 + fo2);
        f16x2 v2 = *(const f16x2*)(hp + (size_t)c2 * 64 + fo2);
        f16x2 v3 = *(const f16x2*)(hp + (size_t)c3 * 64 + fo2);
        ACC2(v0); ACC2(v1); ACC2(v2); ACC2(v3);
    }
    for (; e < s1; ++e) {
        int c0 = col[e];
        f16x2 v0 = *(const f16x2*)(hp + (size_t)c0 * 64 + fo2);
        ACC2(v0);
    }
    float c = (float)(deg > 0 ? deg : 1);
    float ic = 1.f / c;
    float2 sc2 = *(const float2*)(aff + fo2);
    float2 sh2 = *(const float2*)(aff + 64 + fo2);
    float sum0, sum1, max0, max1, mean0, mean1, var0, var1;
    if (deg == 0) {
        sum0 = sum1 = max0 = max1 = mean0 = mean1 = var0 = var1 = 0.f;
    } else {
        // stats of (sc*x + sh): sum' = sc*sum + c*sh; max' = sc*max + sh (sc>0);
        // mean' = sc*mean + sh; var' = sc^2 * relu(sq/c - mean^2)
        sum0 = fmaf(sc2.x, sa, c * sh2.x);
        sum1 = fmaf(sc2.y, sb, c * sh2.y);
        max0 = fmaf(sc2.x, (float)mx[0], sh2.x);
        max1 = fmaf(sc2.y, (float)mx[1], sh2.y);
        float m0 = sa * ic, m1 = sb * ic;
        mean0 = fmaf(sc2.x, m0, sh2.x);
        mean1 = fmaf(sc2.y, m1, sh2.y);
        var0 = sc2.x * sc2.x * fmaxf(fmaf(-m0, m0, qa * ic), 0.f);
        var1 = sc2.y * sc2.y * fmaxf(fmaf(-m1, m1, qb * ic), 0.f);
    }
    size_t b = (size_t)node * 256 + fo2;
    ushort2 o;
    o.x = f2h(sum0); o.y = f2h(sum1);  *(ushort2*)(baseF + b) = o;
    o.x = f2h(max0); o.y = f2h(max1);  *(ushort2*)(baseF + b + 64) = o;
    o.x = f2h(mean0); o.y = f2h(mean1); *(ushort2*)(baseF + b + 128) = o;
    o.x = f2h(var0); o.y = f2h(var1);  *(ushort2*)(baseF + b + 192) = o;
    if (fl == 0) cnt[node] = c;
}

// ---------------------------------------------------------------- fused per-layer MLP
// Phase0: PNA triple GEMM (f16 MFMA, K=256, weights LDS-staged per 64-k chunk)
// Phase1: +bias +scalers +BN-affine residual -> bufA (f16, LDS)
// Phase2: nn1 GEMM (f16 MFMA from bufA) + relu -> bufB
// Phase3: nn2 GEMM + relu -> bufA + bnstat partials
// Phase4: coalesced hOut16 store + bnstat reduce. Block = 256 thr / 128 nodes.
__global__ __launch_bounds__(256) void k_mlp(const unsigned short* __restrict__ baseF,
                                             const float* __restrict__ cnt,
                                             const unsigned short* __restrict__ mWF,
                                             const float* __restrict__ mb,
                                             const unsigned short* __restrict__ hres16,
                                             const float* __restrict__ aff,
                                             const unsigned short* __restrict__ w1F,
                                             const float* __restrict__ b1,
                                             const unsigned short* __restrict__ w2F,
                                             const float* __restrict__ b2,
                                             float* __restrict__ bnstat,
                                             unsigned short* __restrict__ hOut16, int N) {
    __shared__ char smem[61440];
    _Float16* ldsW = (_Float16*)smem;             // 24 KB (reused as `red` later)
    _Float16* bufA = (_Float16*)(smem + 24576);   // [128][72] f16
    _Float16* bufB = bufA + 128 * 72;             // [128][72] f16
    float* red = (float*)smem;                    // 8 KB reuse of ldsW region

    int t = threadIdx.x;
    int wave = t >> 6, lane = t & 63;
    int r16 = lane & 15, quad = lane >> 4;
    int n0 = blockIdx.x * 128;
    int m0 = n0 + wave * 32;

    // ---------------- Phase 0: base[N,256] x 3 matrices
    const _Float16* aptr0 = (const _Float16*)baseF + (size_t)(m0 + r16) * 256 + quad * 8;
    const _Float16* aptr1 = aptr0 + 16 * 256;
    f32x4 acc0[12], acc1[12];
#pragma unroll
    for (int i = 0; i < 12; i++) {
        acc0[i] = (f32x4){0.f, 0.f, 0.f, 0.f};
        acc1[i] = (f32x4){0.f, 0.f, 0.f, 0.f};
    }
    f16x8 a00 = *(const f16x8*)(aptr0 + 0);
    f16x8 a01 = *(const f16x8*)(aptr1 + 0);
    f16x8 a10 = *(const f16x8*)(aptr0 + 32);
    f16x8 a11 = *(const f16x8*)(aptr1 + 32);

#pragma unroll 1
    for (int chunk = 0; chunk < 4; chunk++) {
        if (chunk) __syncthreads();
#pragma unroll
        for (int rb = 0; rb < 24; rb += 4) {
            int rec = rb + wave;
            int s = rec / 12, tile = rec % 12;
            int mat = tile >> 2, nt = tile & 3;
            uint4 v = *(const uint4*)(mWF + (size_t)(nt * 16 + r16) * 768 + mat * 256
                                      + chunk * 64 + s * 32 + quad * 8);
            *(uint4*)((unsigned short*)ldsW + rec * 512 + lane * 8) = v;
        }
        __syncthreads();
        f16x8 n00, n01, n10, n11;
        if (chunk < 3) {
            int ko = (chunk + 1) * 64;
            n00 = *(const f16x8*)(aptr0 + ko);
            n01 = *(const f16x8*)(aptr1 + ko);
            n10 = *(const f16x8*)(aptr0 + ko + 32);
            n11 = *(const f16x8*)(aptr1 + ko + 32);
        }
#pragma unroll
        for (int s = 0; s < 2; s++) {
            f16x8 af0 = s ? a10 : a00;
            f16x8 af1 = s ? a11 : a01;
#pragma unroll
            for (int tile = 0; tile < 12; tile++) {
                f16x8 wF = *(const f16x8*)(ldsW + (s * 12 + tile) * 512 + lane * 8);
                acc0[tile] = __builtin_amdgcn_mfma_f32_16x16x32_f16(af0, wF, acc0[tile], 0, 0, 0);
                acc1[tile] = __builtin_amdgcn_mfma_f32_16x16x32_f16(af1, wF, acc1[tile], 0, 0, 0);
            }
        }
        a00 = n00; a01 = n01; a10 = n10; a11 = n11;
    }
    __syncthreads();

    // ---------------- Phase 1a: residual copy into bufA (coalesced)
    {
        int nl = t >> 1, fo = (t & 1) * 32;
        int gn = n0 + nl;
        uint4* dp = (uint4*)(bufA + nl * 72 + fo);
        if (gn < N) {
            const uint4* sp = (const uint4*)(hres16 + (size_t)gn * 64 + fo);
            dp[0] = sp[0]; dp[1] = sp[1]; dp[2] = sp[2]; dp[3] = sp[3];
        } else {
            uint4 z = make_uint4(0, 0, 0, 0);
            dp[0] = z; dp[1] = z; dp[2] = z; dp[3] = z;
        }
    }
    __syncthreads();

    // ---------------- Phase 1b: combine accs + bias + scalers + affine residual
    float scf[4], shf[4], mbv[4];
#pragma unroll
    for (int nt = 0; nt < 4; nt++) {
        int f = nt * 16 + r16;
        scf[nt] = aff[f]; shf[nt] = aff[64 + f]; mbv[nt] = mb[f];
    }
#pragma unroll
    for (int mt = 0; mt < 2; mt++) {
#pragma unroll
        for (int i = 0; i < 4; i++) {
            int nl = wave * 32 + mt * 16 + quad * 4 + i;
            int gn = n0 + nl;
            if (gn < N) {
                float c = cnt[gn];
                float amp = c / DELTA, att = DELTA / c;
                f32x4* a = mt ? acc1 : acc0;
#pragma unroll
                for (int nt = 0; nt < 4; nt++) {
                    int f = nt * 16 + r16;
                    float r = (float)bufA[nl * 72 + f];
                    float v = a[nt][i] + amp * a[4 + nt][i] + att * a[8 + nt][i]
                            + mbv[nt] + fmaf(r, scf[nt], shf[nt]);
                    bufA[nl * 72 + f] = (_Float16)v;
                }
            }
        }
    }
    __syncthreads();

    // ---------------- Phase 2: nn1 (relu(t @ W1 + b1)) -> bufB
    f32x4 accN[8];
#pragma unroll
    for (int i = 0; i < 8; i++) accN[i] = (f32x4){0.f, 0.f, 0.f, 0.f};
#pragma unroll
    for (int s = 0; s < 2; s++) {
        f16x8 fA0 = *(const f16x8*)(bufA + (wave * 32 + r16) * 72 + s * 32 + quad * 8);
        f16x8 fA1 = *(const f16x8*)(bufA + (wave * 32 + 16 + r16) * 72 + s * 32 + quad * 8);
#pragma unroll
        for (int nt = 0; nt < 4; nt++) {
            f16x8 wB = *(const f16x8*)((const _Float16*)w1F + (size_t)(nt * 16 + r16) * 64
                                       + s * 32 + quad * 8);
            accN[nt]     = __builtin_amdgcn_mfma_f32_16x16x32_f16(fA0, wB, accN[nt], 0, 0, 0);
            accN[4 + nt] = __builtin_amdgcn_mfma_f32_16x16x32_f16(fA1, wB, accN[4 + nt], 0, 0, 0);
        }
    }
    float b1v[4];
#pragma unroll
    for (int nt = 0; nt < 4; nt++) b1v[nt] = b1[nt * 16 + r16];
#pragma unroll
    for (int mt = 0; mt < 2; mt++) {
#pragma unroll
        for (int i = 0; i < 4; i++) {
            int nl = wave * 32 + mt * 16 + quad * 4 + i;
#pragma unroll
            for (int nt = 0; nt < 4; nt++) {
                float v = fmaxf(accN[mt * 4 + nt][i] + b1v[nt], 0.f);
                bufB[nl * 72 + nt * 16 + r16] = (_Float16)v;
            }
        }
    }
    __syncthreads();

    // ---------------- Phase 3: nn2 (relu(u @ W2 + b2)) -> bufA + bnstat partials
    f32x4 accM[8];
#pragma unroll
    for (int i = 0; i < 8; i++) accM[i] = (f32x4){0.f, 0.f, 0.f, 0.f};
#pragma unroll
    for (int s = 0; s < 2; s++) {
        f16x8 fA0 = *(const f16x8*)(bufB + (wave * 32 + r16) * 72 + s * 32 + quad * 8);
        f16x8 fA1 = *(const f16x8*)(bufB + (wave * 32 + 16 + r16) * 72 + s * 32 + quad * 8);
#pragma unroll
        for (int nt = 0; nt < 4; nt++) {
            f16x8 wB = *(const f16x8*)((const _Float16*)w2F + (size_t)(nt * 16 + r16) * 64
                                       + s * 32 + quad * 8);
            accM[nt]     = __builtin_amdgcn_mfma_f32_16x16x32_f16(fA0, wB, accM[nt], 0, 0, 0);
            accM[4 + nt] = __builtin_amdgcn_mfma_f32_16x16x32_f16(fA1, wB, accM[4 + nt], 0, 0, 0);
        }
    }
    float b2v[4], s1[4], s2[4];
#pragma unroll
    for (int nt = 0; nt < 4; nt++) {
        b2v[nt] = b2[nt * 16 + r16]; s1[nt] = 0.f; s2[nt] = 0.f;
    }
#pragma unroll
    for (int mt = 0; mt < 2; mt++) {
#pragma unroll
        for (int i = 0; i < 4; i++) {
            int nl = wave * 32 + mt * 16 + quad * 4 + i;
            bool ok = (n0 + nl) < N;
#pragma unroll
            for (int nt = 0; nt < 4; nt++) {
                float v = fmaxf(accM[mt * 4 + nt][i] + b2v[nt], 0.f);
                if (ok) { s1[nt] += v; s2[nt] = fmaf(v, v, s2[nt]); }
                bufA[nl * 72 + nt * 16 + r16] = (_Float16)v;
            }
        }
    }
#pragma unroll
    for (int nt = 0; nt < 4; nt++) {
        int row = wave * 4 + quad;
        red[row * 64 + nt * 16 + r16] = s1[nt];
        red[1024 + row * 64 + nt * 16 + r16] = s2[nt];
    }
    __syncthreads();

    // ---------------- Phase 4: coalesced store + bnstat reduce
    {
        int nl = t >> 1, fo = (t & 1) * 32;
        int gn = n0 + nl;
        if (gn < N) {
            const uint4* sp = (const uint4*)(bufA + nl * 72 + fo);
            uint4* dp = (uint4*)(hOut16 + (size_t)gn * 64 + fo);
            dp[0] = sp[0]; dp[1] = sp[1]; dp[2] = sp[2]; dp[3] = sp[3];
        }
    }
    if (t < 128) {
        int d = t & 63, part = t >> 6;
        float tot = 0.f;
#pragma unroll
        for (int r = 0; r < 16; r++) tot += red[part * 1024 + r * 64 + d];
        atomicAdd(&bnstat[part * 64 + d], tot);
    }
}

// ---------------------------------------------------------------- 64x64 GEMM (encoder only)
#define FMA16(ACC0, ACC1, ACC2, ACC3, A, W)                                \
    do {                                                                   \
        ACC0.x = fmaf(A.x, W.x, ACC0.x); ACC0.y = fmaf(A.x, W.y, ACC0.y);  \
        ACC0.z = fmaf(A.x, W.z, ACC0.z); ACC0.w = fmaf(A.x, W.w, ACC0.w);  \
        ACC1.x = fmaf(A.y, W.x, ACC1.x); ACC1.y = fmaf(A.y, W.y, ACC1.y);  \
        ACC1.z = fmaf(A.y, W.z, ACC1.z); ACC1.w = fmaf(A.y, W.w, ACC1.w);  \
        ACC2.x = fmaf(A.z, W.x, ACC2.x); ACC2.y = fmaf(A.z, W.y, ACC2.y);  \
        ACC2.z = fmaf(A.z, W.z, ACC2.z); ACC2.w = fmaf(A.z, W.w, ACC2.w);  \
        ACC3.x = fmaf(A.w, W.x, ACC3.x); ACC3.y = fmaf(A.w, W.y, ACC3.y);  \
        ACC3.z = fmaf(A.w, W.z, ACC3.z); ACC3.w = fmaf(A.w, W.w, ACC3.w);  \
    } while (0)

__global__ __launch_bounds__(256) void k_gemm64(const float* __restrict__ in,
                                                const float* __restrict__ W,
                                                const float* __restrict__ bias,
                                                unsigned short* __restrict__ out16, int N) {
    __shared__ float sInT[64][64];  // [k][node]
    __shared__ float sWT[64][64];   // [k][feat]
    int t = threadIdx.x;
    int tx = t & 15, ty = t >> 4;
    int n0 = blockIdx.x * 64;
    int c4 = tx * 4;
#pragma unroll
    for (int ch = 0; ch < 4; ch++) {
        int row = ch * 16 + ty;
        float4 v = make_float4(0.f, 0.f, 0.f, 0.f);
        if (n0 + row < N) v = *(const float4*)(in + (size_t)(n0 + row) * 64 + c4);
        sInT[c4 + 0][row] = v.x; sInT[c4 + 1][row] = v.y;
        sInT[c4 + 2][row] = v.z; sInT[c4 + 3][row] = v.w;
        float4 w = *(const float4*)(W + (size_t)row * 64 + c4);
        sWT[c4 + 0][row] = w.x; sWT[c4 + 1][row] = w.y;
        sWT[c4 + 2][row] = w.z; sWT[c4 + 3][row] = w.w;
    }
    __syncthreads();
    float4 acc0 = make_float4(0.f, 0.f, 0.f, 0.f);
    float4 acc1 = acc0, acc2 = acc0, acc3 = acc0;
#pragma unroll 8
    for (int k = 0; k < 64; k++) {
        float4 a = *(const float4*)(&sInT[k][ty * 4]);
        float4 w = *(const float4*)(&sWT[k][tx * 4]);
        FMA16(acc0, acc1, acc2, acc3, a, w);
    }
    float4 b4 = *(const float4*)(bias + tx * 4);
#pragma unroll
    for (int i = 0; i < 4; i++) {
        int n = n0 + ty * 4 + i;
        if (n < N) {
            float4 v = (i == 0) ? acc0 : (i == 1) ? acc1 : (i == 2) ? acc2 : acc3;
            v.x += b4.x; v.y += b4.y; v.z += b4.z; v.w += b4.w;
            ushort4 o;
            o.x = f2h(v.x); o.y = f2h(v.y); o.z = f2h(v.z); o.w = f2h(v.w);
            *(ushort4*)(out16 + (size_t)n * 64 + tx * 4) = o;
        }
    }
}

// ---------------------------------------------------------------- pool (batch sorted; BN fused; f16 in)
__global__ void k_pool(const unsigned short* __restrict__ h16, const int* __restrict__ batch,
                       const float* __restrict__ aff, float* __restrict__ g, int N) {
    int d = threadIdx.x & 63, r = threadIdx.x >> 6;
    float sc = aff[d], sh = aff[64 + d];
    const _Float16* hp = (const _Float16*)h16;
    int nbase = blockIdx.x * 32;
    float acc = 0.f;
    int gcur = -1;
    for (int i = 0; i < 8; i++) {
        int n = nbase + i * 4 + r;
        if (n < N) {
            int gb = batch[n];
            if (gb != gcur) {
                if (gcur >= 0) atomicAdd(&g[gcur * 64 + d], acc);
                acc = 0.f; gcur = gb;
            }
            acc += fmaf((float)hp[(size_t)n * 64 + d], sc, sh);
        }
    }
    if (gcur >= 0) atomicAdd(&g[gcur * 64 + d], acc);
}

// ---------------------------------------------------------------- head: relu(g@fc1)+fc2
__global__ void k_head(const float* __restrict__ g, const float* __restrict__ fc1W,
                       const float* __restrict__ fc1b, const float* __restrict__ fc2W,
                       const float* __restrict__ fc2b, float* __restrict__ out) {
    __shared__ float sg[64], sg1[64];
    int gi = blockIdx.x, t = threadIdx.x;
    sg[t] = g[gi * 64 + t];
    __syncthreads();
    float a = fc1b[t];
    for (int k = 0; k < 64; k++) a = fmaf(sg[k], fc1W[t * 64 + k], a);
    sg1[t] = fmaxf(a, 0.f);
    __syncthreads();
    if (t < 16) {
        float o = fc2b[t];
        for (int k = 0; k < 64; k++) o = fmaf(sg1[k], fc2W[t * 64 + k], o);
        out[gi * 16 + t] = o;
    }
}

// ---------------------------------------------------------------- launcher
extern "C" void kernel_launch(void* const* d_in, const int* in_sizes, int n_in,
                              void* d_out, int out_size, void* d_ws, size_t ws_size,
                              hipStream_t stream) {
    const float* x       = (const float*)d_in[0];
    const int*   eidx    = (const int*)d_in[1];
    const int*   batch   = (const int*)d_in[2];
    const float* encW    = (const float*)d_in[3];
    const float* encb    = (const float*)d_in[4];
    const float* nnW1    = (const float*)d_in[5];
    const float* nnb1    = (const float*)d_in[6];
    const float* nnW2    = (const float*)d_in[7];
    const float* nnb2    = (const float*)d_in[8];
    const float* mlpW    = (const float*)d_in[9];
    const float* mlpb    = (const float*)d_in[10];
    const float* bnG     = (const float*)d_in[11];
    const float* bnB     = (const float*)d_in[12];
    const float* fc1W    = (const float*)d_in[13];
    const float* fc1b    = (const float*)d_in[14];
    const float* fc2W    = (const float*)d_in[15];
    const float* fc2b    = (const float*)d_in[16];
    float* out = (float*)d_out;

    const int N = in_sizes[0] / 64;
    const int E = in_sizes[1] / 2;
    const int G = 512;
    const int* src = eidx;
    const int* dst = eidx + E;
    const int npp = (N + 7) / 8;  // nodes per XCD partition

    // workspace layout
    char* ws = (char*)d_ws;
    size_t off = 0;
    auto alloc = [&](size_t bytes) { size_t r = off; off = (off + bytes + 255) & ~(size_t)255; return r; };
    int*   deg     = (int*)(ws + alloc((size_t)(N + 1) * 4));
    int*   rowptr  = (int*)(ws + alloc((size_t)(N + 1) * 4));
    int*   bsums   = (int*)(ws + alloc(1024 * 4));
    int*   fill    = (int*)(ws + alloc((size_t)N * 4));
    int*   col     = (int*)(ws + alloc((size_t)E * 4));
    float* cnt     = (float*)(ws + alloc((size_t)N * 4));
    unsigned short* baseF = (unsigned short*)(ws + alloc((size_t)N * 256 * 2 + 131072));  // +pad for OOB tile reads
    unsigned short* hC16 = (unsigned short*)(ws + alloc((size_t)N * 64 * 2 + 32768));     // +pad
    unsigned short* mWF  = (unsigned short*)(ws + alloc((size_t)5 * 64 * 768 * 2));
    unsigned short* nW1F = (unsigned short*)(ws + alloc((size_t)5 * 64 * 64 * 2));
    unsigned short* nW2F = (unsigned short*)(ws + alloc((size_t)5 * 64 * 64 * 2));
    float* bnstats = (float*)(ws + alloc(5 * 128 * 4));
    float* affbuf  = (float*)(ws + alloc(6 * 128 * 4));
    float* gpool   = (float*)(ws + alloc((size_t)G * 64 * 4));

    hipMemsetAsync(deg, 0, (size_t)(N + 1) * 4, stream);
    hipMemsetAsync(fill, 0, (size_t)N * 4, stream);
    hipMemsetAsync(bnstats, 0, 5 * 128 * 4, stream);
    hipMemsetAsync(gpool, 0, (size_t)G * 64 * 4, stream);

    int total = N + 1;
    int nscan = (total + SCAN_B - 1) / SCAN_B;
    int ngrid64 = (N + 63) / 64;
    int ngrid128 = (N + 127) / 128;

    k_degree<<<1024, 256, 0, stream>>>(dst, deg, E, npp);
    k_scan_block<<<nscan, SCAN_B, 0, stream>>>(deg, rowptr, bsums, total);
    k_scan_tops<<<1, SCAN_B, 0, stream>>>(bsums, nscan);
    k_scan_add<<<nscan, SCAN_B, 0, stream>>>(rowptr, bsums, total);
    k_fill<<<1024, 256, 0, stream>>>(src, dst, rowptr, fill, col, E, npp);

    // cast weights to f16
    k_castw<<<240, 256, 0, stream>>>(mlpW, mWF, 61440);
    k_castw<<<20, 256, 0, stream>>>(nnW1, nW1F, 5120);
    k_castw<<<20, 256, 0, stream>>>(nnW2, nW2F, 5120);
    k_ident<<<1, 128, 0, stream>>>(affbuf);

    // encoder: hC16 = f16(x @ encW.T + encb)
    k_gemm64<<<ngrid64, 256, 0, stream>>>(x, encW, encb, hC16, N);

    for (int i = 0; i < 5; i++) {
        const float* aff = affbuf + i * 128;
        k_agg<<<(N + 7) / 8, 256, 0, stream>>>(hC16, rowptr, col, aff, baseF, cnt, N);
        k_mlp<<<ngrid128, 256, 0, stream>>>(baseF, cnt,
                                            mWF + (size_t)i * 64 * 768, mlpb + i * 64,
                                            hC16, aff,
                                            nW1F + (size_t)i * 4096, nnb1 + i * 64,
                                            nW2F + (size_t)i * 4096, nnb2 + i * 64,
                                            bnstats + i * 128, hC16, N);
        k_bnfin<<<1, 64, 0, stream>>>(bnstats + i * 128, bnG + i * 64, bnB + i * 64,
                                      affbuf + (i + 1) * 128, 1.f / (float)N);
    }

    k_pool<<<(N + 31) / 32, 256, 0, stream>>>(hC16, batch, affbuf + 5 * 128, gpool, N);
    k_head<<<G, 64, 0, stream>>>(gpool, fc1W, fc1b, fc2W, fc2b, out);
}